// Round 7
// baseline (2066.088 us; speedup 1.0000x reference)
//
#include <hip/hip_runtime.h>
#include <hip/hip_bf16.h>
#include <math.h>

#define RSQ 0.99999500003749969f   // 1/sqrt(1+1e-5)
#define SLOPE 0.01f

typedef __attribute__((ext_vector_type(8))) short short8;
typedef __attribute__((ext_vector_type(4))) float f32x4;

__device__ __forceinline__ float sigmoidf_(float x){ return 1.0f/(1.0f+expf(-x)); }

__device__ __forceinline__ unsigned short f2bf(float f){
    unsigned u = __float_as_uint(f);
    u += 0x7fff + ((u >> 16) & 1);      // RNE
    return (unsigned short)(u >> 16);
}
__device__ __forceinline__ float bf2f(unsigned short s){
    return __uint_as_float(((unsigned)s) << 16);
}

// ---------------- mask: prod_k cos(fW*rng + fB) ----------------
__global__ void mask_partial_kernel(const float* __restrict__ fW, const float* __restrict__ fB,
                                    float* __restrict__ partial)
{
    int p = blockIdx.x*256 + threadIdx.x;   // 0..15902
    if (p >= 15903) return;
    int w = p % 513;
    float r = (float)(w + 1);
    int k0 = blockIdx.y * 32;
    float prod = 1.0f;
    for (int k = k0; k < k0 + 32; ++k) {
        float a = fW[(size_t)k*15903 + p] * r + fB[(size_t)k*15903 + p];
        prod *= cosf(a);
    }
    partial[blockIdx.y*15903 + p] = prod;
}

__global__ void mask_finalize_apply(const float* __restrict__ partial, const float* __restrict__ x,
                                    float* __restrict__ xm)
{
    int p = blockIdx.x*256 + threadIdx.x;
    if (p >= 15903) return;
    float m = 1.0f;
    #pragma unroll
    for (int c = 0; c < 32; ++c) m *= partial[c*15903 + p];
    for (int n = 0; n < 32; ++n)
        xm[(size_t)n*15903 + p] = x[(size_t)n*15903 + p] * m;
}

// ---------------- weight transforms ----------------
// OIHW fp32 -> [tap][co][ci] bf16
__global__ void wtrans9_kernel(const float* __restrict__ w, unsigned short* __restrict__ o,
                               int Cout, int Cin)
{
    int idx = blockIdx.x*256 + threadIdx.x;
    int cc = Cout*Cin;
    if (idx >= 9*cc) return;
    int tap = idx / cc;
    int r = idx - tap*cc;
    int co = r / Cin, ci = r - co*Cin;
    int kh = tap/3, kw = tap - kh*3;
    o[idx] = f2bf(w[((size_t)(co*Cin + ci)*3 + kh)*3 + kw]);
}
__global__ void wtrans1_kernel(const float* __restrict__ w, unsigned short* __restrict__ o, int total)
{
    int idx = blockIdx.x*256 + threadIdx.x;
    if (idx < total) o[idx] = f2bf(w[idx]);
}

// whh (1024,256) fp32 -> MFMA-fragment-contiguous bf16
__global__ void whh_frag_kernel(const float* __restrict__ whh, unsigned short* __restrict__ out)
{
    int tid = blockIdx.x*256 + threadIdx.x;  // 262144 exact
    int e    = tid & 7;
    int lane = (tid >> 3) & 63;
    int kc   = (tid >> 9) & 7;
    int u0   = (tid >> 12) & 15;
    int g    = tid >> 16;
    int j = (g << 8) + (u0 << 4) + (lane & 15);
    int k = (kc << 5) + ((lane >> 4) << 3) + e;
    out[tid] = f2bf(whh[(size_t)j*256 + k]);
}

// ---------------- conv1: Cin=1 direct, fp32 in -> bf16 NHWC out ----------------
__launch_bounds__(256)
__global__ void conv1_kernel(const float* __restrict__ xm, const float* __restrict__ w1,
                             const float* __restrict__ g, const float* __restrict__ b,
                             unsigned short* __restrict__ O)
{
    __shared__ float wl[576];
    __shared__ float sg[64], sb[64];
    int tid = threadIdx.x;
    if (tid < 64) { sg[tid] = g[tid]*RSQ; sb[tid] = b[tid]; }
    for (int i = tid; i < 576; i += 256) wl[i] = w1[i];
    __syncthreads();
    int px = blockIdx.x*256 + tid;
    int n = blockIdx.z;
    if (px >= 15903) return;
    int h = px / 513, w = px - h*513;
    const float* xp = xm + (size_t)n*15903;
    float v[9];
    #pragma unroll
    for (int dh = 0; dh < 3; ++dh)
      #pragma unroll
      for (int dw = 0; dw < 3; ++dw) {
        int hh = h+dh-1, ww = w+dw-1;
        bool ok = ((unsigned)hh < 31u) && ((unsigned)ww < 513u);
        v[dh*3+dw] = ok ? xp[hh*513 + ww] : 0.f;
      }
    unsigned short* op = O + ((size_t)n*15903 + px)*64;
    #pragma unroll
    for (int c8 = 0; c8 < 8; ++c8) {
        unsigned tmp[8];
        #pragma unroll
        for (int j = 0; j < 8; ++j) {
            int co = c8*8 + j;
            const float* wr = &wl[co*9];
            float a = 0.f;
            #pragma unroll
            for (int t2 = 0; t2 < 9; ++t2) a += wr[t2]*v[t2];
            a = a*sg[co] + sb[co];
            a = (a >= 0.f) ? a : SLOPE*a;
            tmp[j] = f2bf(a);
        }
        uint4 pk;
        pk.x = tmp[0] | (tmp[1]<<16);
        pk.y = tmp[2] | (tmp[3]<<16);
        pk.z = tmp[4] | (tmp[5]<<16);
        pk.w = tmp[6] | (tmp[7]<<16);
        *(uint4*)(op + c8*8) = pk;
    }
}

// ---------------- row-tiled implicit-GEMM 3x3 conv (+1x1 shortcut) via MFMA ----------------
// Block = (w-tile, h) x co64 x n. Wave: 16 co x TPX*16 px (one h row).
// TPX=8 for wide layers, TPX=2 for W=32.
template<int TPX>
__launch_bounds__(256, 3)
__global__ void conv_row_kernel(const unsigned short* __restrict__ X,
                                const unsigned short* __restrict__ W9,
                                const unsigned short* __restrict__ Xs,
                                const unsigned short* __restrict__ Ws,
                                unsigned short* __restrict__ O,
                                int H, int W, int WT, int Cin, int Cs, int Cout,
                                const float* __restrict__ g, const float* __restrict__ b)
{
    const int lane = threadIdx.x & 63;
    const int wave = threadIdx.x >> 6;
    const int co64 = blockIdx.y * 64 + wave * 16;
    const int n  = blockIdx.z;
    const int wt = blockIdx.x % WT;
    const int h  = blockIdx.x / WT;
    const int w0 = wt * (TPX*16);
    const int l15 = lane & 15;
    const int kl = (lane >> 4) * 8;
    const short8 zf = {0,0,0,0,0,0,0,0};

    const unsigned short* Xn = X + (size_t)n * H * W * Cin;
    f32x4 acc[TPX] = {};

    const bool interior = (w0 >= 1) && (w0 + TPX*16 + 1 <= W);

    #pragma unroll
    for (int dh = 0; dh < 3; ++dh) {
        int hh = h - 1 + dh;
        if ((unsigned)hh >= (unsigned)H) continue;          // wave-uniform skip
        const unsigned short* rp = Xn + (size_t)hh * W * Cin;
        if (interior) {
            #pragma unroll
            for (int dw = 0; dw < 3; ++dw) {
                const unsigned short* ap = W9 + ((size_t)(dh*3+dw)*Cout + co64 + l15)*Cin + kl;
                const unsigned short* bp = rp + (size_t)(w0 - 1 + dw + l15)*Cin + kl;
                for (int k0 = 0; k0 < Cin; k0 += 32) {
                    short8 a = *(const short8*)(ap + k0);
                    #pragma unroll
                    for (int t = 0; t < TPX; ++t) {
                        short8 bv = *(const short8*)(bp + (size_t)t*16*Cin + k0);
                        acc[t] = __builtin_amdgcn_mfma_f32_16x16x32_bf16(a, bv, acc[t], 0, 0, 0);
                    }
                }
            }
        } else {
            #pragma unroll
            for (int dw = 0; dw < 3; ++dw) {
                const unsigned short* ap = W9 + ((size_t)(dh*3+dw)*Cout + co64 + l15)*Cin + kl;
                bool v[TPX]; const unsigned short* bp[TPX];
                #pragma unroll
                for (int t = 0; t < TPX; ++t) {
                    int ww = w0 - 1 + dw + t*16 + l15;
                    v[t] = (unsigned)ww < (unsigned)W;
                    bp[t] = rp + (size_t)(v[t] ? ww : 0)*Cin + kl;
                }
                for (int k0 = 0; k0 < Cin; k0 += 32) {
                    short8 a = *(const short8*)(ap + k0);
                    #pragma unroll
                    for (int t = 0; t < TPX; ++t) {
                        short8 bv = v[t] ? *(const short8*)(bp[t] + k0) : zf;
                        acc[t] = __builtin_amdgcn_mfma_f32_16x16x32_bf16(a, bv, acc[t], 0, 0, 0);
                    }
                }
            }
        }
    }

    if (Ws) {   // fused 1x1 shortcut
        const unsigned short* rp = Xs + ((size_t)n * H + h) * W * Cs;
        const unsigned short* ap = Ws + ((size_t)(co64 + l15))*Cs + kl;
        bool v[TPX]; const unsigned short* bp[TPX];
        #pragma unroll
        for (int t = 0; t < TPX; ++t) {
            int ww = w0 + t*16 + l15;
            v[t] = ww < W;
            bp[t] = rp + (size_t)(v[t] ? ww : 0)*Cs + kl;
        }
        for (int k0 = 0; k0 < Cs; k0 += 32) {
            short8 a = *(const short8*)(ap + k0);
            #pragma unroll
            for (int t = 0; t < TPX; ++t) {
                short8 bv = v[t] ? *(const short8*)(bp[t] + k0) : zf;
                acc[t] = __builtin_amdgcn_mfma_f32_16x16x32_bf16(a, bv, acc[t], 0, 0, 0);
            }
        }
    }

    // epilogue: bn + lrelu -> bf16 NHWC
    int cb = co64 + (lane >> 4)*4;
    float s0 = g[cb+0]*RSQ, s1 = g[cb+1]*RSQ, s2 = g[cb+2]*RSQ, s3 = g[cb+3]*RSQ;
    float o0 = b[cb+0], o1 = b[cb+1], o2 = b[cb+2], o3 = b[cb+3];
    #pragma unroll
    for (int t = 0; t < TPX; ++t) {
        int w = w0 + t*16 + l15;
        if (w < W) {
            float v0 = acc[t][0]*s0 + o0; v0 = (v0 >= 0.f) ? v0 : SLOPE*v0;
            float v1 = acc[t][1]*s1 + o1; v1 = (v1 >= 0.f) ? v1 : SLOPE*v1;
            float v2 = acc[t][2]*s2 + o2; v2 = (v2 >= 0.f) ? v2 : SLOPE*v2;
            float v3 = acc[t][3]*s3 + o3; v3 = (v3 >= 0.f) ? v3 : SLOPE*v3;
            uint2 pk;
            pk.x = (unsigned)f2bf(v0) | ((unsigned)f2bf(v1) << 16);
            pk.y = (unsigned)f2bf(v2) | ((unsigned)f2bf(v3) << 16);
            *(uint2*)(O + (((size_t)n*H + h)*W + w)*Cout + cb) = pk;
        }
    }
}

// ---------------- generic px-tiled conv (kept for W=8 layers) ----------------
__launch_bounds__(256)
__global__ void conv_mfma_kernel(const unsigned short* __restrict__ X,
                                 const unsigned short* __restrict__ W9,
                                 const unsigned short* __restrict__ Xs,
                                 const unsigned short* __restrict__ Ws,
                                 unsigned short* __restrict__ O,
                                 int H, int W, int Cin, int Cs, int Cout,
                                 const float* __restrict__ g, const float* __restrict__ b)
{
    const int HW = H * W;
    const int lane = threadIdx.x & 63;
    const int wave = threadIdx.x >> 6;
    const int co64 = blockIdx.y * 64 + wave * 16;
    const int n = blockIdx.z;
    const int px0 = blockIdx.x * 64;
    const int l15 = lane & 15;
    const int kl = (lane >> 4) * 8;
    const short8 zf = {0,0,0,0,0,0,0,0};

    int hh_[4], ww_[4]; bool pv[4];
    #pragma unroll
    for (int t = 0; t < 4; ++t) {
        int px = px0 + t*16 + l15;
        pv[t] = px < HW;
        int pc = pv[t] ? px : 0;
        hh_[t] = pc / W;
        ww_[t] = pc - hh_[t]*W;
    }

    const unsigned short* Xn = X + (size_t)n * HW * Cin;
    f32x4 acc0 = {0,0,0,0}, acc1 = {0,0,0,0}, acc2 = {0,0,0,0}, acc3 = {0,0,0,0};

    for (int tap = 0; tap < 9; ++tap) {
        int dh = tap/3 - 1, dw = tap - (tap/3)*3 - 1;
        const short8* ap = (const short8*)(W9 + ((size_t)tap*Cout + co64 + l15)*Cin + kl);
        const short8* bp[4]; bool v[4];
        #pragma unroll
        for (int t = 0; t < 4; ++t) {
            int hh = hh_[t] + dh, ww = ww_[t] + dw;
            v[t] = pv[t] && ((unsigned)hh < (unsigned)H) && ((unsigned)ww < (unsigned)W);
            int p2 = v[t] ? (hh*W + ww) : 0;
            bp[t] = (const short8*)(Xn + (size_t)p2*Cin + kl);
        }
        for (int k0 = 0; k0 < Cin; k0 += 32) {
            int ko = k0 >> 3;
            short8 a  = ap[ko];
            short8 b0 = v[0] ? bp[0][ko] : zf;
            short8 b1 = v[1] ? bp[1][ko] : zf;
            short8 b2 = v[2] ? bp[2][ko] : zf;
            short8 b3 = v[3] ? bp[3][ko] : zf;
            acc0 = __builtin_amdgcn_mfma_f32_16x16x32_bf16(a, b0, acc0, 0, 0, 0);
            acc1 = __builtin_amdgcn_mfma_f32_16x16x32_bf16(a, b1, acc1, 0, 0, 0);
            acc2 = __builtin_amdgcn_mfma_f32_16x16x32_bf16(a, b2, acc2, 0, 0, 0);
            acc3 = __builtin_amdgcn_mfma_f32_16x16x32_bf16(a, b3, acc3, 0, 0, 0);
        }
    }

    if (Ws) {
        const unsigned short* X2n = Xs + (size_t)n * HW * Cs;
        const short8* ap = (const short8*)(Ws + ((size_t)(co64 + l15))*Cs + kl);
        const short8* bp[4];
        #pragma unroll
        for (int t = 0; t < 4; ++t) {
            int p2 = pv[t] ? (hh_[t]*W + ww_[t]) : 0;
            bp[t] = (const short8*)(X2n + (size_t)p2*Cs + kl);
        }
        for (int k0 = 0; k0 < Cs; k0 += 32) {
            int ko = k0 >> 3;
            short8 a  = ap[ko];
            short8 b0 = pv[0] ? bp[0][ko] : zf;
            short8 b1 = pv[1] ? bp[1][ko] : zf;
            short8 b2 = pv[2] ? bp[2][ko] : zf;
            short8 b3 = pv[3] ? bp[3][ko] : zf;
            acc0 = __builtin_amdgcn_mfma_f32_16x16x32_bf16(a, b0, acc0, 0, 0, 0);
            acc1 = __builtin_amdgcn_mfma_f32_16x16x32_bf16(a, b1, acc1, 0, 0, 0);
            acc2 = __builtin_amdgcn_mfma_f32_16x16x32_bf16(a, b2, acc2, 0, 0, 0);
            acc3 = __builtin_amdgcn_mfma_f32_16x16x32_bf16(a, b3, acc3, 0, 0, 0);
        }
    }

    int cb = co64 + (lane >> 4)*4;
    float s0 = g[cb+0]*RSQ, s1 = g[cb+1]*RSQ, s2 = g[cb+2]*RSQ, s3 = g[cb+3]*RSQ;
    float o0 = b[cb+0], o1 = b[cb+1], o2 = b[cb+2], o3 = b[cb+3];

#define EPI(ACC, T) do { \
    if (pv[T]) { \
        int px = px0 + (T)*16 + l15; \
        float v0 = ACC[0]*s0 + o0; v0 = (v0 >= 0.f) ? v0 : SLOPE*v0; \
        float v1 = ACC[1]*s1 + o1; v1 = (v1 >= 0.f) ? v1 : SLOPE*v1; \
        float v2 = ACC[2]*s2 + o2; v2 = (v2 >= 0.f) ? v2 : SLOPE*v2; \
        float v3 = ACC[3]*s3 + o3; v3 = (v3 >= 0.f) ? v3 : SLOPE*v3; \
        uint2 pk; \
        pk.x = (unsigned)f2bf(v0) | ((unsigned)f2bf(v1) << 16); \
        pk.y = (unsigned)f2bf(v2) | ((unsigned)f2bf(v3) << 16); \
        *(uint2*)(O + ((size_t)n*HW + px)*Cout + cb) = pk; \
    } \
} while(0)
    EPI(acc0, 0); EPI(acc1, 1); EPI(acc2, 2); EPI(acc3, 3);
#undef EPI
}

// ---------------- maxpool(1,4) VALID on NHWC bf16 ----------------
__global__ void pool_nhwc_kernel(const unsigned short* __restrict__ in,
                                 unsigned short* __restrict__ out,
                                 int W, int Wout, int C, int total8)
{
    int idx = blockIdx.x*256 + threadIdx.x;
    if (idx >= total8) return;
    int c8 = idx % (C >> 3);
    int r = idx / (C >> 3);
    int w = r % Wout;
    int nh = r / Wout;
    const unsigned short* ip = in + (((size_t)nh*W) + (size_t)w*4)*C + c8*8;
    float m0=-1e30f,m1=-1e30f,m2=-1e30f,m3=-1e30f,m4=-1e30f,m5=-1e30f,m6=-1e30f,m7=-1e30f;
    #pragma unroll
    for (int i = 0; i < 4; ++i) {
        uint4 u = *(const uint4*)(ip + (size_t)i*C);
        m0 = fmaxf(m0, bf2f((unsigned short)(u.x & 0xffff)));
        m1 = fmaxf(m1, bf2f((unsigned short)(u.x >> 16)));
        m2 = fmaxf(m2, bf2f((unsigned short)(u.y & 0xffff)));
        m3 = fmaxf(m3, bf2f((unsigned short)(u.y >> 16)));
        m4 = fmaxf(m4, bf2f((unsigned short)(u.z & 0xffff)));
        m5 = fmaxf(m5, bf2f((unsigned short)(u.z >> 16)));
        m6 = fmaxf(m6, bf2f((unsigned short)(u.w & 0xffff)));
        m7 = fmaxf(m7, bf2f((unsigned short)(u.w >> 16)));
    }
    uint4 ov;
    ov.x = (unsigned)f2bf(m0) | ((unsigned)f2bf(m1) << 16);
    ov.y = (unsigned)f2bf(m2) | ((unsigned)f2bf(m3) << 16);
    ov.z = (unsigned)f2bf(m4) | ((unsigned)f2bf(m5) << 16);
    ov.w = (unsigned)f2bf(m6) | ((unsigned)f2bf(m7) << 16);
    *(uint4*)(out + (size_t)idx*8) = ov;
}

// ---------------- feats: [n][31][2][256] bf16 NHWC -> [n][31][512] fp32 ----------------
__global__ void feats_kernel(const unsigned short* __restrict__ p4, float* __restrict__ fe)
{
    int idx = blockIdx.x*256 + threadIdx.x;   // 507904
    int cw = idx & 511;
    int nh = idx >> 9;
    int c = cw >> 1, w = cw & 1;
    fe[idx] = bf2f(p4[((size_t)nh*2 + w)*256 + c]);
}

// ---------------- tiled SGEMM: C[M,N] = A[M,K] @ B[N,K]^T + bias(+bias2) ----------------
#define GM 32
#define GN 64
#define GK 32
template<int XPOSE>
__launch_bounds__(256)
__global__ void gemm_bias_kernel(const float* __restrict__ A, const float* __restrict__ B,
                                 const float* __restrict__ bias, const float* __restrict__ bias2,
                                 float* __restrict__ C, int M, int N, int K)
{
    __shared__ float As[GM][GK+1];
    __shared__ float Bs[GN][GK+1];
    int m0 = blockIdx.x*GM, n0 = blockIdx.y*GN;
    int tid = threadIdx.x;
    int mi = tid >> 4;
    int ni = (tid & 15) * 4;
    float acc[2][4] = {};

    for (int k0 = 0; k0 < K; k0 += GK) {
        for (int i = tid; i < GM*GK; i += 256) {
            int r = i >> 5, c = i & 31;
            int m = m0 + r;
            As[r][c] = (m < M) ? A[(size_t)m*K + k0 + c] : 0.f;
        }
        for (int i = tid; i < GN*GK; i += 256) {
            int r = i >> 5, c = i & 31;
            int n = n0 + r;
            Bs[r][c] = (n < N) ? B[(size_t)n*K + k0 + c] : 0.f;
        }
        __syncthreads();
        #pragma unroll
        for (int kk = 0; kk < GK; ++kk) {
            float a0 = As[mi][kk], a1 = As[mi+16][kk];
            float b0 = Bs[ni][kk], b1 = Bs[ni+1][kk], b2 = Bs[ni+2][kk], b3 = Bs[ni+3][kk];
            acc[0][0] += a0*b0; acc[0][1] += a0*b1; acc[0][2] += a0*b2; acc[0][3] += a0*b3;
            acc[1][0] += a1*b0; acc[1][1] += a1*b1; acc[1][2] += a1*b2; acc[1][3] += a1*b3;
        }
        __syncthreads();
    }
    #pragma unroll
    for (int r = 0; r < 2; ++r) {
        int m = m0 + mi + r*16;
        if (m >= M) continue;
        #pragma unroll
        for (int q = 0; q < 4; ++q) {
            int n = n0 + ni + q;
            if (n >= N) continue;
            float v = acc[r][q];
            if (bias)  v += bias[n];
            if (bias2) v += bias2[n];
            if (XPOSE) C[((size_t)(m % 31)*32 + (m / 31))*N + n] = v;
            else       C[(size_t)m*N + n] = v;
        }
    }
}

// ---------------- LSTM scan via MFMA: 4 blocks = (dir x batch-half), 1024 thr ----------------
__launch_bounds__(1024, 4)
__global__ void lstm_scan_mfma(const float* __restrict__ xpT,
                               const unsigned short* __restrict__ wf,
                               float* __restrict__ hcat)
{
    const int d  = blockIdx.x >> 1;
    const int bh = blockIdx.x & 1;
    const int tid = threadIdx.x;
    const int u0 = tid >> 6;
    const int lane = tid & 63;
    const int l15 = lane & 15;
    const int q = lane >> 4;

    __shared__ unsigned short hbuf[2][4096];

    ((int4*)hbuf)[tid] = make_int4(0,0,0,0);
    __syncthreads();

    const unsigned short* wfd = wf + (size_t)d*262144;
    const float* xpd = xpT + (size_t)d*992*1024 + (size_t)bh*16*1024;

    float c0=0.f, c1=0.f, c2=0.f, c3=0.f;
    const int ubase = u0*16 + q*4;
    const int rb = l15*512 + q*16;
    const int xr = (l15&7)<<4;
    const size_t wo0 = (size_t)u0*8*512 + (size_t)lane*8;

    for (int s = 0; s < 31; ++s) {
        const int t = d ? (30 - s) : s;
        const int cur = s & 1, nxt = cur ^ 1;
        const float* xb = xpd + (size_t)t*32768 + (size_t)l15*1024;

        float4 xi = *(const float4*)(xb + ubase);
        float4 xf = *(const float4*)(xb + 256 + ubase);
        float4 xg = *(const float4*)(xb + 512 + ubase);
        float4 xo = *(const float4*)(xb + 768 + ubase);

        f32x4 a0={0,0,0,0}, a1={0,0,0,0}, a2={0,0,0,0}, a3={0,0,0,0};
        const char* hb = (const char*)hbuf[cur];

        short8 w0 = *(const short8*)(wfd + wo0);
        short8 w1 = *(const short8*)(wfd + wo0 + 65536);
        short8 w2 = *(const short8*)(wfd + wo0 + 131072);
        short8 w3 = *(const short8*)(wfd + wo0 + 196608);
        #pragma unroll
        for (int kc = 0; kc < 8; ++kc) {
            short8 n0, n1, n2, n3;
            if (kc < 7) {
                size_t wo = wo0 + (size_t)(kc+1)*512;
                n0 = *(const short8*)(wfd + wo);
                n1 = *(const short8*)(wfd + wo + 65536);
                n2 = *(const short8*)(wfd + wo + 131072);
                n3 = *(const short8*)(wfd + wo + 196608);
            }
            short8 h = *(const short8*)(hb + ((rb + kc*64) ^ xr));
            a0 = __builtin_amdgcn_mfma_f32_16x16x32_bf16(w0, h, a0, 0, 0, 0);
            a1 = __builtin_amdgcn_mfma_f32_16x16x32_bf16(w1, h, a1, 0, 0, 0);
            a2 = __builtin_amdgcn_mfma_f32_16x16x32_bf16(w2, h, a2, 0, 0, 0);
            a3 = __builtin_amdgcn_mfma_f32_16x16x32_bf16(w3, h, a3, 0, 0, 0);
            if (kc < 7) { w0 = n0; w1 = n1; w2 = n2; w3 = n3; }
        }

        float hv[4];
        {
            float gi=a0[0]+xi.x, gf=a1[0]+xf.x, gg=a2[0]+xg.x, go=a3[0]+xo.x;
            float cn = sigmoidf_(gf)*c0 + sigmoidf_(gi)*tanhf(gg); c0 = cn; hv[0] = sigmoidf_(go)*tanhf(cn);
        }
        {
            float gi=a0[1]+xi.y, gf=a1[1]+xf.y, gg=a2[1]+xg.y, go=a3[1]+xo.y;
            float cn = sigmoidf_(gf)*c1 + sigmoidf_(gi)*tanhf(gg); c1 = cn; hv[1] = sigmoidf_(go)*tanhf(cn);
        }
        {
            float gi=a0[2]+xi.z, gf=a1[2]+xf.z, gg=a2[2]+xg.z, go=a3[2]+xo.z;
            float cn = sigmoidf_(gf)*c2 + sigmoidf_(gi)*tanhf(gg); c2 = cn; hv[2] = sigmoidf_(go)*tanhf(cn);
        }
        {
            float gi=a0[3]+xi.w, gf=a1[3]+xf.w, gg=a2[3]+xg.w, go=a3[3]+xo.w;
            float cn = sigmoidf_(gf)*c3 + sigmoidf_(gi)*tanhf(gg); c3 = cn; hv[3] = sigmoidf_(go)*tanhf(cn);
        }

        short4 hp;
        hp.x = (short)f2bf(hv[0]); hp.y = (short)f2bf(hv[1]);
        hp.z = (short)f2bf(hv[2]); hp.w = (short)f2bf(hv[3]);
        *(short4*)((char*)hbuf[nxt] + ((l15*512 + ubase*2) ^ xr)) = hp;
        int bg = bh*16 + l15;
        *(float4*)(&hcat[((size_t)bg*31 + t)*512 + (size_t)d*256 + ubase]) =
            make_float4(hv[0], hv[1], hv[2], hv[3]);

        __syncthreads();
    }
}

extern "C" void kernel_launch(void* const* d_in, const int* in_sizes, int n_in,
                              void* d_out, int out_size, void* d_ws, size_t ws_size,
                              hipStream_t stream)
{
    const float* x    = (const float*)d_in[0];
    const float* fW   = (const float*)d_in[1];
    const float* fB   = (const float*)d_in[2];
    const float* cbw1 = (const float*)d_in[3];
    const float* cbg  = (const float*)d_in[4];
    const float* cbb  = (const float*)d_in[5];
    const float* cbw2 = (const float*)d_in[6];
    const float* r1pg = (const float*)d_in[7];
    const float* r1pb = (const float*)d_in[8];
    const float* r1wA = (const float*)d_in[9];
    const float* r1g  = (const float*)d_in[10];
    const float* r1b  = (const float*)d_in[11];
    const float* r1wB = (const float*)d_in[12];
    const float* r1s  = (const float*)d_in[13];
    const float* r2pg = (const float*)d_in[14];
    const float* r2pb = (const float*)d_in[15];
    const float* r2wA = (const float*)d_in[16];
    const float* r2g  = (const float*)d_in[17];
    const float* r2b  = (const float*)d_in[18];
    const float* r2wB = (const float*)d_in[19];
    const float* r2s  = (const float*)d_in[20];
    const float* r3pg = (const float*)d_in[21];
    const float* r3pb = (const float*)d_in[22];
    const float* r3wA = (const float*)d_in[23];
    const float* r3g  = (const float*)d_in[24];
    const float* r3b  = (const float*)d_in[25];
    const float* r3wB = (const float*)d_in[26];
    const float* r3s  = (const float*)d_in[27];
    const float* pbg  = (const float*)d_in[28];
    const float* pbb  = (const float*)d_in[29];
    const float* wih_f = (const float*)d_in[30];
    const float* whh_f = (const float*)d_in[31];
    const float* bih_f = (const float*)d_in[32];
    const float* bhh_f = (const float*)d_in[33];
    const float* wih_b = (const float*)d_in[34];
    const float* whh_b = (const float*)d_in[35];
    const float* bih_b = (const float*)d_in[36];
    const float* bhh_b = (const float*)d_in[37];
    const float* clsw  = (const float*)d_in[38];
    const float* clsb  = (const float*)d_in[39];
    float* out = (float*)d_out;
    float* ws  = (float*)d_ws;

    // ---- workspace sizing (floats) ----
    const size_t FIXEDF = 962560 + 508896 + 508896 + 253952 + 507904
                        + 262144 + 2031616 + 507904;
    const size_t PCF = 508896*2 + 126976 + 63488 + 23808;
    int NC = 0;
    const int cands[6] = {32,16,8,4,2,1};
    for (int i = 0; i < 6; ++i) {
        if ((FIXEDF + (size_t)cands[i]*PCF)*sizeof(float) <= ws_size) { NC = cands[i]; break; }
    }
    if (!NC) return;

    float* p = ws;
    unsigned short* WTR = (unsigned short*)p; p += 962560;
    float* P   = p; p += 508896;
    float* XM  = p; p += 508896;
    unsigned short* XP4 = (unsigned short*)p; p += 253952;
    float* FE  = p; p += 507904;
    unsigned short* WF = (unsigned short*)p; p += 262144;
    float* XPT = p; p += 2031616;
    float* HC  = p; p += 507904;
    unsigned short* REG1 = (unsigned short*)p; p += (size_t)NC*508896;
    unsigned short* REG2 = (unsigned short*)p; p += (size_t)NC*508896;
    unsigned short* XP1c = (unsigned short*)p; p += (size_t)NC*126976;
    unsigned short* XP2c = (unsigned short*)p; p += (size_t)NC*63488;
    unsigned short* XP3c = (unsigned short*)p; p += (size_t)NC*23808;

    unsigned short* w2T  = WTR + 0;
    unsigned short* r1AT = WTR + 36864;
    unsigned short* r1BT = WTR + 110592;
    unsigned short* r1ST = WTR + 258048;
    unsigned short* r2AT = WTR + 266240;
    unsigned short* r2BT = WTR + 487424;
    unsigned short* r2ST = WTR + 819200;
    unsigned short* r3AT = WTR + 843776;
    unsigned short* r3BT = WTR + 1286144;
    unsigned short* r3ST = WTR + 1875968;

    auto cdiv = [](int a, int b){ return (a + b - 1) / b; };

    // ---- weight transforms ----
    wtrans9_kernel<<<cdiv(9*64*64,256),   256, 0, stream>>>(cbw2, w2T, 64, 64);
    wtrans9_kernel<<<cdiv(9*128*64,256),  256, 0, stream>>>(r1wA, r1AT, 128, 64);
    wtrans9_kernel<<<cdiv(9*128*128,256), 256, 0, stream>>>(r1wB, r1BT, 128, 128);
    wtrans1_kernel<<<cdiv(128*64,256),    256, 0, stream>>>(r1s, r1ST, 128*64);
    wtrans9_kernel<<<cdiv(9*192*128,256), 256, 0, stream>>>(r2wA, r2AT, 192, 128);
    wtrans9_kernel<<<cdiv(9*192*192,256), 256, 0, stream>>>(r2wB, r2BT, 192, 192);
    wtrans1_kernel<<<cdiv(192*128,256),   256, 0, stream>>>(r2s, r2ST, 192*128);
    wtrans9_kernel<<<cdiv(9*256*192,256), 256, 0, stream>>>(r3wA, r3AT, 256, 192);
    wtrans9_kernel<<<cdiv(9*256*256,256), 256, 0, stream>>>(r3wB, r3BT, 256, 256);
    wtrans1_kernel<<<cdiv(256*192,256),   256, 0, stream>>>(r3s, r3ST, 256*192);
    whh_frag_kernel<<<1024, 256, 0, stream>>>(whh_f, WF);
    whh_frag_kernel<<<1024, 256, 0, stream>>>(whh_b, WF + 262144);

    // ---- frontend mask ----
    mask_partial_kernel<<<dim3(63, 32), 256, 0, stream>>>(fW, fB, P);
    mask_finalize_apply<<<63, 256, 0, stream>>>(P, x, XM);

    // ---- conv stack, chunked over batch ----
    for (int c0 = 0; c0 < 32; c0 += NC) {
        const float* xmc = XM + (size_t)c0*15903;
        conv1_kernel<<<dim3(63, 1, NC), 256, 0, stream>>>(xmc, cbw1, cbg, cbb, REG1);
        // conv2: 64->64, W=513, TPX=8 (WT=5)
        conv_row_kernel<8><<<dim3(5*31, 1, NC), 256, 0, stream>>>(
            REG1, w2T, nullptr, nullptr, REG2, 31, 513, 5, 64, 0, 64, r1pg, r1pb);
        pool_nhwc_kernel<<<cdiv(NC*31*128*8,256), 256, 0, stream>>>(REG2, XP1c, 513, 128, 64, NC*31*128*8);
        // r1A: 64->128, W=128, TPX=8 (WT=1)
        conv_row_kernel<8><<<dim3(31, 2, NC), 256, 0, stream>>>(
            XP1c, r1AT, nullptr, nullptr, REG1, 31, 128, 1, 64, 0, 128, r1g, r1b);
        // r1B + shortcut
        conv_row_kernel<8><<<dim3(31, 2, NC), 256, 0, stream>>>(
            REG1, r1BT, XP1c, r1ST, REG2, 31, 128, 1, 128, 64, 128, r2pg, r2pb);
        pool_nhwc_kernel<<<cdiv(NC*31*32*16,256), 256, 0, stream>>>(REG2, XP2c, 128, 32, 128, NC*31*32*16);
        // r2A: 128->192, W=32, TPX=2 (WT=1)
        conv_row_kernel<2><<<dim3(31, 3, NC), 256, 0, stream>>>(
            XP2c, r2AT, nullptr, nullptr, REG1, 31, 32, 1, 128, 0, 192, r2g, r2b);
        // r2B + shortcut
        conv_row_kernel<2><<<dim3(31, 3, NC), 256, 0, stream>>>(
            REG1, r2BT, XP2c, r2ST, REG2, 31, 32, 1, 192, 128, 192, r3pg, r3pb);
        pool_nhwc_kernel<<<cdiv(NC*31*8*24,256), 256, 0, stream>>>(REG2, XP3c, 32, 8, 192, NC*31*8*24);
        // r3 (W=8): generic kernel
        conv_mfma_kernel<<<dim3(cdiv(31*8,64), 4, NC), 256, 0, stream>>>(
            XP3c, r3AT, nullptr, nullptr, REG1, 31, 8, 192, 0, 256, r3g, r3b);
        conv_mfma_kernel<<<dim3(cdiv(31*8,64), 4, NC), 256, 0, stream>>>(
            REG1, r3BT, XP3c, r3ST, REG2, 31, 8, 256, 192, 256, pbg, pbb);
        pool_nhwc_kernel<<<cdiv(NC*31*2*32,256), 256, 0, stream>>>(
            REG2, XP4 + (size_t)c0*15872, 8, 2, 256, NC*31*2*32);
    }

    // feats (32,31,512) fp32
    feats_kernel<<<1984, 256, 0, stream>>>(XP4, FE);

    // LSTM input projections -> xpT [d][t][b][j]
    gemm_bias_kernel<1><<<dim3(31, 16), 256, 0, stream>>>(FE, wih_f, bih_f, bhh_f, XPT,           992, 1024, 512);
    gemm_bias_kernel<1><<<dim3(31, 16), 256, 0, stream>>>(FE, wih_b, bih_b, bhh_b, XPT + 1015808, 992, 1024, 512);

    // fused bidirectional scan (4 blocks: dir x batch-half)
    lstm_scan_mfma<<<4, 1024, 0, stream>>>(XPT, WF, HC);

    // classifier -> d_out (32,31,722)
    gemm_bias_kernel<0><<<dim3(31, 12), 256, 0, stream>>>(HC, clsw, clsb, nullptr, out, 992, 722, 512);
}

// Round 8
// 2062.565 us; speedup vs baseline: 1.0017x; 1.0017x over previous
//
#include <hip/hip_runtime.h>
#include <hip/hip_bf16.h>
#include <math.h>

#define RSQ 0.99999500003749969f   // 1/sqrt(1+1e-5)
#define SLOPE 0.01f

typedef __attribute__((ext_vector_type(8))) short short8;
typedef __attribute__((ext_vector_type(4))) float f32x4;

__device__ __forceinline__ float sigmoidf_(float x){ return 1.0f/(1.0f+expf(-x)); }

__device__ __forceinline__ unsigned short f2bf(float f){
    unsigned u = __float_as_uint(f);
    u += 0x7fff + ((u >> 16) & 1);      // RNE
    return (unsigned short)(u >> 16);
}
__device__ __forceinline__ float bf2f(unsigned short s){
    return __uint_as_float(((unsigned)s) << 16);
}

// ---------------- mask: prod_k cos(fW*rng + fB) ----------------
__global__ void mask_partial_kernel(const float* __restrict__ fW, const float* __restrict__ fB,
                                    float* __restrict__ partial)
{
    int p = blockIdx.x*256 + threadIdx.x;   // 0..15902
    if (p >= 15903) return;
    int w = p % 513;
    float r = (float)(w + 1);
    int k0 = blockIdx.y * 32;
    float prod = 1.0f;
    for (int k = k0; k < k0 + 32; ++k) {
        float a = fW[(size_t)k*15903 + p] * r + fB[(size_t)k*15903 + p];
        prod *= cosf(a);
    }
    partial[blockIdx.y*15903 + p] = prod;
}

__global__ void mask_finalize_apply(const float* __restrict__ partial, const float* __restrict__ x,
                                    float* __restrict__ xm)
{
    int p = blockIdx.x*256 + threadIdx.x;
    if (p >= 15903) return;
    float m = 1.0f;
    #pragma unroll
    for (int c = 0; c < 32; ++c) m *= partial[c*15903 + p];
    for (int n = 0; n < 32; ++n)
        xm[(size_t)n*15903 + p] = x[(size_t)n*15903 + p] * m;
}

// ---------------- weight transforms ----------------
__global__ void wtrans9_kernel(const float* __restrict__ w, unsigned short* __restrict__ o,
                               int Cout, int Cin)
{
    int idx = blockIdx.x*256 + threadIdx.x;
    int cc = Cout*Cin;
    if (idx >= 9*cc) return;
    int tap = idx / cc;
    int r = idx - tap*cc;
    int co = r / Cin, ci = r - co*Cin;
    int kh = tap/3, kw = tap - kh*3;
    o[idx] = f2bf(w[((size_t)(co*Cin + ci)*3 + kh)*3 + kw]);
}
__global__ void wtrans1_kernel(const float* __restrict__ w, unsigned short* __restrict__ o, int total)
{
    int idx = blockIdx.x*256 + threadIdx.x;
    if (idx < total) o[idx] = f2bf(w[idx]);
}

// whh (1024,256) fp32 -> MFMA-fragment-contiguous bf16
__global__ void whh_frag_kernel(const float* __restrict__ whh, unsigned short* __restrict__ out)
{
    int tid = blockIdx.x*256 + threadIdx.x;  // 262144 exact
    int e    = tid & 7;
    int lane = (tid >> 3) & 63;
    int kc   = (tid >> 9) & 7;
    int u0   = (tid >> 12) & 15;
    int g    = tid >> 16;
    int j = (g << 8) + (u0 << 4) + (lane & 15);
    int k = (kc << 5) + ((lane >> 4) << 3) + e;
    out[tid] = f2bf(whh[(size_t)j*256 + k]);
}

// ---------------- conv1: Cin=1 direct, fp32 in -> bf16 NHWC out (padded stride 515) ----------------
__launch_bounds__(256)
__global__ void conv1_kernel(const float* __restrict__ xm, const float* __restrict__ w1,
                             const float* __restrict__ g, const float* __restrict__ b,
                             unsigned short* __restrict__ O)
{
    __shared__ float wl[576];
    __shared__ float sg[64], sb[64];
    int tid = threadIdx.x;
    if (tid < 64) { sg[tid] = g[tid]*RSQ; sb[tid] = b[tid]; }
    for (int i = tid; i < 576; i += 256) wl[i] = w1[i];
    __syncthreads();
    int px = blockIdx.x*256 + tid;
    int n = blockIdx.z;
    if (px >= 15903) return;
    int h = px / 513, w = px - h*513;
    const float* xp = xm + (size_t)n*15903;
    float v[9];
    #pragma unroll
    for (int dh = 0; dh < 3; ++dh)
      #pragma unroll
      for (int dw = 0; dw < 3; ++dw) {
        int hh = h+dh-1, ww = w+dw-1;
        bool ok = ((unsigned)hh < 31u) && ((unsigned)ww < 513u);
        v[dh*3+dw] = ok ? xp[hh*513 + ww] : 0.f;
      }
    unsigned short* op = O + (((size_t)(n*31 + h))*515 + (w + 1))*64;
    #pragma unroll
    for (int c8 = 0; c8 < 8; ++c8) {
        unsigned tmp[8];
        #pragma unroll
        for (int j = 0; j < 8; ++j) {
            int co = c8*8 + j;
            const float* wr = &wl[co*9];
            float a = 0.f;
            #pragma unroll
            for (int t2 = 0; t2 < 9; ++t2) a += wr[t2]*v[t2];
            a = a*sg[co] + sb[co];
            a = (a >= 0.f) ? a : SLOPE*a;
            tmp[j] = f2bf(a);
        }
        uint4 pk;
        pk.x = tmp[0] | (tmp[1]<<16);
        pk.y = tmp[2] | (tmp[3]<<16);
        pk.z = tmp[4] | (tmp[5]<<16);
        pk.w = tmp[6] | (tmp[7]<<16);
        *(uint4*)(op + c8*8) = pk;
    }
}

// ---------------- padded row-tiled implicit-GEMM 3x3 conv (+1x1 shortcut) via MFMA ----------------
// Input X: NHWC bf16 with padded width Wp (cols 0 and Wv+1 are zero halos).
// Output O: stride WpO, col offset OOFF. All loops compile-time; no masks on loads.
template<int CIN, int TPX, int CS>
__launch_bounds__(256, 2)
__global__ void conv_row_kernel(const unsigned short* __restrict__ X,
                                const unsigned short* __restrict__ W9,
                                const unsigned short* __restrict__ Xs,
                                const unsigned short* __restrict__ Ws,
                                unsigned short* __restrict__ O,
                                int Wp, int Wv, int WT, int W0OFF, int WpS,
                                int WpO, int OOFF, int Cout,
                                const float* __restrict__ g, const float* __restrict__ b)
{
    const int lane = threadIdx.x & 63;
    const int wave = threadIdx.x >> 6;
    const int cob  = blockIdx.y * 64 + wave * 16;
    const int n  = blockIdx.z;
    const int wt = blockIdx.x % WT;
    const int h  = blockIdx.x / WT;
    const int w0 = W0OFF + wt * (TPX*16);
    const int l15 = lane & 15;
    const int kl = (lane >> 4) * 8;

    f32x4 acc[TPX] = {};

    #pragma unroll
    for (int dh = 0; dh < 3; ++dh) {
        int hh = h - 1 + dh;
        if ((unsigned)hh >= 31u) continue;                  // wave-uniform
        const unsigned short* rp = X + ((size_t)(n*31 + hh) * Wp)*CIN;
        const unsigned short* bbase[TPX];
        #pragma unroll
        for (int t = 0; t < TPX; ++t)
            bbase[t] = rp + (size_t)(w0 + t*16 + l15)*CIN + kl;
        #pragma unroll
        for (int dw = 0; dw < 3; ++dw) {
            const unsigned short* ap = W9 + ((size_t)(dh*3+dw)*Cout + cob + l15)*CIN + kl;
            #pragma unroll
            for (int k0 = 0; k0 < CIN; k0 += 32) {
                short8 a = *(const short8*)(ap + k0);
                #pragma unroll
                for (int t = 0; t < TPX; ++t) {
                    short8 bv = *(const short8*)(bbase[t] + dw*CIN + k0);
                    acc[t] = __builtin_amdgcn_mfma_f32_16x16x32_bf16(a, bv, acc[t], 0, 0, 0);
                }
            }
        }
    }

    if (CS > 0) {   // fused 1x1 shortcut from padded Xs (center tap -> col +1)
        const unsigned short* rs = Xs + ((size_t)(n*31 + h) * WpS)*CS;
        const unsigned short* ap2 = Ws + (size_t)(cob + l15)*CS + kl;
        const unsigned short* sbase[TPX];
        #pragma unroll
        for (int t = 0; t < TPX; ++t)
            sbase[t] = rs + (size_t)(w0 + t*16 + l15 + 1)*CS + kl;
        #pragma unroll
        for (int k0 = 0; k0 < (CS > 0 ? CS : 32); k0 += 32) {
            short8 a = *(const short8*)(ap2 + k0);
            #pragma unroll
            for (int t = 0; t < TPX; ++t) {
                short8 bv = *(const short8*)(sbase[t] + k0);
                acc[t] = __builtin_amdgcn_mfma_f32_16x16x32_bf16(a, bv, acc[t], 0, 0, 0);
            }
        }
    }

    // epilogue: bn + lrelu -> bf16
    int cb = cob + (lane >> 4)*4;
    float s0 = g[cb+0]*RSQ, s1 = g[cb+1]*RSQ, s2 = g[cb+2]*RSQ, s3 = g[cb+3]*RSQ;
    float o0 = b[cb+0], o1 = b[cb+1], o2 = b[cb+2], o3 = b[cb+3];
    #pragma unroll
    for (int t = 0; t < TPX; ++t) {
        int w = w0 + t*16 + l15;
        if (w < Wv) {
            float v0 = acc[t][0]*s0 + o0; v0 = (v0 >= 0.f) ? v0 : SLOPE*v0;
            float v1 = acc[t][1]*s1 + o1; v1 = (v1 >= 0.f) ? v1 : SLOPE*v1;
            float v2 = acc[t][2]*s2 + o2; v2 = (v2 >= 0.f) ? v2 : SLOPE*v2;
            float v3 = acc[t][3]*s3 + o3; v3 = (v3 >= 0.f) ? v3 : SLOPE*v3;
            uint2 pk;
            pk.x = (unsigned)f2bf(v0) | ((unsigned)f2bf(v1) << 16);
            pk.y = (unsigned)f2bf(v2) | ((unsigned)f2bf(v3) << 16);
            *(uint2*)(O + (((size_t)(n*31 + h))*WpO + w + OOFF)*Cout + cb) = pk;
        }
    }
}

// ---------------- generic px-tiled conv (kept for W=8 layers) ----------------
__launch_bounds__(256)
__global__ void conv_mfma_kernel(const unsigned short* __restrict__ X,
                                 const unsigned short* __restrict__ W9,
                                 const unsigned short* __restrict__ Xs,
                                 const unsigned short* __restrict__ Ws,
                                 unsigned short* __restrict__ O,
                                 int H, int W, int Cin, int Cs, int Cout,
                                 const float* __restrict__ g, const float* __restrict__ b)
{
    const int HW = H * W;
    const int lane = threadIdx.x & 63;
    const int wave = threadIdx.x >> 6;
    const int co64 = blockIdx.y * 64 + wave * 16;
    const int n = blockIdx.z;
    const int px0 = blockIdx.x * 64;
    const int l15 = lane & 15;
    const int kl = (lane >> 4) * 8;
    const short8 zf = {0,0,0,0,0,0,0,0};

    int hh_[4], ww_[4]; bool pv[4];
    #pragma unroll
    for (int t = 0; t < 4; ++t) {
        int px = px0 + t*16 + l15;
        pv[t] = px < HW;
        int pc = pv[t] ? px : 0;
        hh_[t] = pc / W;
        ww_[t] = pc - hh_[t]*W;
    }

    const unsigned short* Xn = X + (size_t)n * HW * Cin;
    f32x4 acc0 = {0,0,0,0}, acc1 = {0,0,0,0}, acc2 = {0,0,0,0}, acc3 = {0,0,0,0};

    for (int tap = 0; tap < 9; ++tap) {
        int dh = tap/3 - 1, dw = tap - (tap/3)*3 - 1;
        const short8* ap = (const short8*)(W9 + ((size_t)tap*Cout + co64 + l15)*Cin + kl);
        const short8* bp[4]; bool v[4];
        #pragma unroll
        for (int t = 0; t < 4; ++t) {
            int hh = hh_[t] + dh, ww = ww_[t] + dw;
            v[t] = pv[t] && ((unsigned)hh < (unsigned)H) && ((unsigned)ww < (unsigned)W);
            int p2 = v[t] ? (hh*W + ww) : 0;
            bp[t] = (const short8*)(Xn + (size_t)p2*Cin + kl);
        }
        for (int k0 = 0; k0 < Cin; k0 += 32) {
            int ko = k0 >> 3;
            short8 a  = ap[ko];
            short8 b0 = v[0] ? bp[0][ko] : zf;
            short8 b1 = v[1] ? bp[1][ko] : zf;
            short8 b2 = v[2] ? bp[2][ko] : zf;
            short8 b3 = v[3] ? bp[3][ko] : zf;
            acc0 = __builtin_amdgcn_mfma_f32_16x16x32_bf16(a, b0, acc0, 0, 0, 0);
            acc1 = __builtin_amdgcn_mfma_f32_16x16x32_bf16(a, b1, acc1, 0, 0, 0);
            acc2 = __builtin_amdgcn_mfma_f32_16x16x32_bf16(a, b2, acc2, 0, 0, 0);
            acc3 = __builtin_amdgcn_mfma_f32_16x16x32_bf16(a, b3, acc3, 0, 0, 0);
        }
    }

    if (Ws) {
        const unsigned short* X2n = Xs + (size_t)n * HW * Cs;
        const short8* ap = (const short8*)(Ws + ((size_t)(co64 + l15))*Cs + kl);
        const short8* bp[4];
        #pragma unroll
        for (int t = 0; t < 4; ++t) {
            int p2 = pv[t] ? (hh_[t]*W + ww_[t]) : 0;
            bp[t] = (const short8*)(X2n + (size_t)p2*Cs + kl);
        }
        for (int k0 = 0; k0 < Cs; k0 += 32) {
            int ko = k0 >> 3;
            short8 a  = ap[ko];
            short8 b0 = pv[0] ? bp[0][ko] : zf;
            short8 b1 = pv[1] ? bp[1][ko] : zf;
            short8 b2 = pv[2] ? bp[2][ko] : zf;
            short8 b3 = pv[3] ? bp[3][ko] : zf;
            acc0 = __builtin_amdgcn_mfma_f32_16x16x32_bf16(a, b0, acc0, 0, 0, 0);
            acc1 = __builtin_amdgcn_mfma_f32_16x16x32_bf16(a, b1, acc1, 0, 0, 0);
            acc2 = __builtin_amdgcn_mfma_f32_16x16x32_bf16(a, b2, acc2, 0, 0, 0);
            acc3 = __builtin_amdgcn_mfma_f32_16x16x32_bf16(a, b3, acc3, 0, 0, 0);
        }
    }

    int cb = co64 + (lane >> 4)*4;
    float s0 = g[cb+0]*RSQ, s1 = g[cb+1]*RSQ, s2 = g[cb+2]*RSQ, s3 = g[cb+3]*RSQ;
    float o0 = b[cb+0], o1 = b[cb+1], o2 = b[cb+2], o3 = b[cb+3];

#define EPI(ACC, T) do { \
    if (pv[T]) { \
        int px = px0 + (T)*16 + l15; \
        float v0 = ACC[0]*s0 + o0; v0 = (v0 >= 0.f) ? v0 : SLOPE*v0; \
        float v1 = ACC[1]*s1 + o1; v1 = (v1 >= 0.f) ? v1 : SLOPE*v1; \
        float v2 = ACC[2]*s2 + o2; v2 = (v2 >= 0.f) ? v2 : SLOPE*v2; \
        float v3 = ACC[3]*s3 + o3; v3 = (v3 >= 0.f) ? v3 : SLOPE*v3; \
        uint2 pk; \
        pk.x = (unsigned)f2bf(v0) | ((unsigned)f2bf(v1) << 16); \
        pk.y = (unsigned)f2bf(v2) | ((unsigned)f2bf(v3) << 16); \
        *(uint2*)(O + ((size_t)n*HW + px)*Cout + cb) = pk; \
    } \
} while(0)
    EPI(acc0, 0); EPI(acc1, 1); EPI(acc2, 2); EPI(acc3, 3);
#undef EPI
}

// ---------------- maxpool(1,4) VALID on NHWC bf16, padded-out capable ----------------
__global__ void pool_nhwc_kernel(const unsigned short* __restrict__ in,
                                 unsigned short* __restrict__ out,
                                 int Win, int Wout, int WpO, int OOFF, int C, int total8)
{
    int idx = blockIdx.x*256 + threadIdx.x;
    if (idx >= total8) return;
    int c8 = idx % (C >> 3);
    int r = idx / (C >> 3);
    int w = r % Wout;
    int nh = r / Wout;
    const unsigned short* ip = in + (((size_t)nh*Win) + (size_t)w*4)*C + c8*8;
    float m0=-1e30f,m1=-1e30f,m2=-1e30f,m3=-1e30f,m4=-1e30f,m5=-1e30f,m6=-1e30f,m7=-1e30f;
    #pragma unroll
    for (int i = 0; i < 4; ++i) {
        uint4 u = *(const uint4*)(ip + (size_t)i*C);
        m0 = fmaxf(m0, bf2f((unsigned short)(u.x & 0xffff)));
        m1 = fmaxf(m1, bf2f((unsigned short)(u.x >> 16)));
        m2 = fmaxf(m2, bf2f((unsigned short)(u.y & 0xffff)));
        m3 = fmaxf(m3, bf2f((unsigned short)(u.y >> 16)));
        m4 = fmaxf(m4, bf2f((unsigned short)(u.z & 0xffff)));
        m5 = fmaxf(m5, bf2f((unsigned short)(u.z >> 16)));
        m6 = fmaxf(m6, bf2f((unsigned short)(u.w & 0xffff)));
        m7 = fmaxf(m7, bf2f((unsigned short)(u.w >> 16)));
    }
    uint4 ov;
    ov.x = (unsigned)f2bf(m0) | ((unsigned)f2bf(m1) << 16);
    ov.y = (unsigned)f2bf(m2) | ((unsigned)f2bf(m3) << 16);
    ov.z = (unsigned)f2bf(m4) | ((unsigned)f2bf(m5) << 16);
    ov.w = (unsigned)f2bf(m6) | ((unsigned)f2bf(m7) << 16);
    *(uint4*)(out + (((size_t)nh*WpO) + w + OOFF)*C + c8*8) = ov;
}

// ---------------- feats: [n][31][2][256] bf16 NHWC -> [n][31][512] fp32 ----------------
__global__ void feats_kernel(const unsigned short* __restrict__ p4, float* __restrict__ fe)
{
    int idx = blockIdx.x*256 + threadIdx.x;   // 507904
    int cw = idx & 511;
    int nh = idx >> 9;
    int c = cw >> 1, w = cw & 1;
    fe[idx] = bf2f(p4[((size_t)nh*2 + w)*256 + c]);
}

// ---------------- tiled SGEMM: C[M,N] = A[M,K] @ B[N,K]^T + bias(+bias2) ----------------
#define GM 32
#define GN 64
#define GK 32
template<int XPOSE>
__launch_bounds__(256)
__global__ void gemm_bias_kernel(const float* __restrict__ A, const float* __restrict__ B,
                                 const float* __restrict__ bias, const float* __restrict__ bias2,
                                 float* __restrict__ C, int M, int N, int K)
{
    __shared__ float As[GM][GK+1];
    __shared__ float Bs[GN][GK+1];
    int m0 = blockIdx.x*GM, n0 = blockIdx.y*GN;
    int tid = threadIdx.x;
    int mi = tid >> 4;
    int ni = (tid & 15) * 4;
    float acc[2][4] = {};

    for (int k0 = 0; k0 < K; k0 += GK) {
        for (int i = tid; i < GM*GK; i += 256) {
            int r = i >> 5, c = i & 31;
            int m = m0 + r;
            As[r][c] = (m < M) ? A[(size_t)m*K + k0 + c] : 0.f;
        }
        for (int i = tid; i < GN*GK; i += 256) {
            int r = i >> 5, c = i & 31;
            int n = n0 + r;
            Bs[r][c] = (n < N) ? B[(size_t)n*K + k0 + c] : 0.f;
        }
        __syncthreads();
        #pragma unroll
        for (int kk = 0; kk < GK; ++kk) {
            float a0 = As[mi][kk], a1 = As[mi+16][kk];
            float b0 = Bs[ni][kk], b1 = Bs[ni+1][kk], b2 = Bs[ni+2][kk], b3 = Bs[ni+3][kk];
            acc[0][0] += a0*b0; acc[0][1] += a0*b1; acc[0][2] += a0*b2; acc[0][3] += a0*b3;
            acc[1][0] += a1*b0; acc[1][1] += a1*b1; acc[1][2] += a1*b2; acc[1][3] += a1*b3;
        }
        __syncthreads();
    }
    #pragma unroll
    for (int r = 0; r < 2; ++r) {
        int m = m0 + mi + r*16;
        if (m >= M) continue;
        #pragma unroll
        for (int q = 0; q < 4; ++q) {
            int n = n0 + ni + q;
            if (n >= N) continue;
            float v = acc[r][q];
            if (bias)  v += bias[n];
            if (bias2) v += bias2[n];
            if (XPOSE) C[((size_t)(m % 31)*32 + (m / 31))*N + n] = v;
            else       C[(size_t)m*N + n] = v;
        }
    }
}

// ---------------- LSTM scan via MFMA: 4 blocks = (dir x batch-half), 1024 thr ----------------
// wf kc0-1 persistent in VGPRs (loop-invariant); kc2-7 streamed with rolling window.
__launch_bounds__(1024, 4)
__global__ void lstm_scan_mfma(const float* __restrict__ xpT,
                               const unsigned short* __restrict__ wf,
                               float* __restrict__ hcat)
{
    const int d  = blockIdx.x >> 1;
    const int bh = blockIdx.x & 1;
    const int tid = threadIdx.x;
    const int u0 = tid >> 6;
    const int lane = tid & 63;
    const int l15 = lane & 15;
    const int q = lane >> 4;

    __shared__ unsigned short hbuf[2][4096];
    ((int4*)hbuf)[tid] = make_int4(0,0,0,0);
    __syncthreads();

    const unsigned short* wfd = wf + (size_t)d*262144;
    const float* xpd = xpT + (size_t)d*992*1024 + (size_t)bh*16*1024;
    const unsigned short* wp = wfd + u0*4096 + lane*8;

    float c0=0.f, c1=0.f, c2=0.f, c3=0.f;
    const int ubase = u0*16 + q*4;
    const int rb = l15*512 + q*16;
    const int xr = (l15&7)<<4;

#define WLD(kc,g) (*(const short8*)(wp + (kc)*512 + (g)*65536))
#define HRD(kc)   (*(const short8*)(hb + ((rb + (kc)*64) ^ xr)))
#define MF(w_,h_,a_) a_ = __builtin_amdgcn_mfma_f32_16x16x32_bf16(w_, h_, a_, 0, 0, 0)
    const short8 p00=WLD(0,0), p01=WLD(0,1), p02=WLD(0,2), p03=WLD(0,3);
    const short8 p10=WLD(1,0), p11=WLD(1,1), p12=WLD(1,2), p13=WLD(1,3);

    for (int s = 0; s < 31; ++s) {
        const int t = d ? (30 - s) : s;
        const int cur = s & 1, nxt = cur ^ 1;
        const float* xb = xpd + (size_t)t*32768 + (size_t)l15*1024;
        float4 xi = *(const float4*)(xb + ubase);
        float4 xf = *(const float4*)(xb + 256 + ubase);
        float4 xg = *(const float4*)(xb + 512 + ubase);
        float4 xo = *(const float4*)(xb + 768 + ubase);

        const char* hb = (const char*)hbuf[cur];
        f32x4 a0={0,0,0,0}, a1={0,0,0,0}, a2={0,0,0,0}, a3={0,0,0,0};

        short8 s20=WLD(2,0), s21=WLD(2,1), s22=WLD(2,2), s23=WLD(2,3);
        { short8 h0 = HRD(0); MF(p00,h0,a0); MF(p01,h0,a1); MF(p02,h0,a2); MF(p03,h0,a3); }
        short8 s30=WLD(3,0), s31=WLD(3,1), s32=WLD(3,2), s33=WLD(3,3);
        { short8 h1 = HRD(1); MF(p10,h1,a0); MF(p11,h1,a1); MF(p12,h1,a2); MF(p13,h1,a3); }
        short8 s40=WLD(4,0), s41=WLD(4,1), s42=WLD(4,2), s43=WLD(4,3);
        { short8 h2 = HRD(2); MF(s20,h2,a0); MF(s21,h2,a1); MF(s22,h2,a2); MF(s23,h2,a3); }
        short8 s50=WLD(5,0), s51=WLD(5,1), s52=WLD(5,2), s53=WLD(5,3);
        { short8 h3 = HRD(3); MF(s30,h3,a0); MF(s31,h3,a1); MF(s32,h3,a2); MF(s33,h3,a3); }
        short8 s60=WLD(6,0), s61=WLD(6,1), s62=WLD(6,2), s63=WLD(6,3);
        { short8 h4 = HRD(4); MF(s40,h4,a0); MF(s41,h4,a1); MF(s42,h4,a2); MF(s43,h4,a3); }
        short8 s70=WLD(7,0), s71=WLD(7,1), s72=WLD(7,2), s73=WLD(7,3);
        { short8 h5 = HRD(5); MF(s50,h5,a0); MF(s51,h5,a1); MF(s52,h5,a2); MF(s53,h5,a3); }
        { short8 h6 = HRD(6); MF(s60,h6,a0); MF(s61,h6,a1); MF(s62,h6,a2); MF(s63,h6,a3); }
        { short8 h7 = HRD(7); MF(s70,h7,a0); MF(s71,h7,a1); MF(s72,h7,a2); MF(s73,h7,a3); }

        float hv0, hv1, hv2, hv3;
        { float gi=a0[0]+xi.x, gf=a1[0]+xf.x, gg=a2[0]+xg.x, go=a3[0]+xo.x;
          float cn = sigmoidf_(gf)*c0 + sigmoidf_(gi)*tanhf(gg); c0 = cn; hv0 = sigmoidf_(go)*tanhf(cn); }
        { float gi=a0[1]+xi.y, gf=a1[1]+xf.y, gg=a2[1]+xg.y, go=a3[1]+xo.y;
          float cn = sigmoidf_(gf)*c1 + sigmoidf_(gi)*tanhf(gg); c1 = cn; hv1 = sigmoidf_(go)*tanhf(cn); }
        { float gi=a0[2]+xi.z, gf=a1[2]+xf.z, gg=a2[2]+xg.z, go=a3[2]+xo.z;
          float cn = sigmoidf_(gf)*c2 + sigmoidf_(gi)*tanhf(gg); c2 = cn; hv2 = sigmoidf_(go)*tanhf(cn); }
        { float gi=a0[3]+xi.w, gf=a1[3]+xf.w, gg=a2[3]+xg.w, go=a3[3]+xo.w;
          float cn = sigmoidf_(gf)*c3 + sigmoidf_(gi)*tanhf(gg); c3 = cn; hv3 = sigmoidf_(go)*tanhf(cn); }

        short4 hp;
        hp.x = (short)f2bf(hv0); hp.y = (short)f2bf(hv1);
        hp.z = (short)f2bf(hv2); hp.w = (short)f2bf(hv3);
        *(short4*)((char*)hbuf[nxt] + ((l15*512 + ubase*2) ^ xr)) = hp;
        int bg = bh*16 + l15;
        *(float4*)(&hcat[((size_t)bg*31 + t)*512 + (size_t)d*256 + ubase]) =
            make_float4(hv0, hv1, hv2, hv3);

        __syncthreads();
    }
#undef WLD
#undef HRD
#undef MF
}

extern "C" void kernel_launch(void* const* d_in, const int* in_sizes, int n_in,
                              void* d_out, int out_size, void* d_ws, size_t ws_size,
                              hipStream_t stream)
{
    const float* x    = (const float*)d_in[0];
    const float* fW   = (const float*)d_in[1];
    const float* fB   = (const float*)d_in[2];
    const float* cbw1 = (const float*)d_in[3];
    const float* cbg  = (const float*)d_in[4];
    const float* cbb  = (const float*)d_in[5];
    const float* cbw2 = (const float*)d_in[6];
    const float* r1pg = (const float*)d_in[7];
    const float* r1pb = (const float*)d_in[8];
    const float* r1wA = (const float*)d_in[9];
    const float* r1g  = (const float*)d_in[10];
    const float* r1b  = (const float*)d_in[11];
    const float* r1wB = (const float*)d_in[12];
    const float* r1s  = (const float*)d_in[13];
    const float* r2pg = (const float*)d_in[14];
    const float* r2pb = (const float*)d_in[15];
    const float* r2wA = (const float*)d_in[16];
    const float* r2g  = (const float*)d_in[17];
    const float* r2b  = (const float*)d_in[18];
    const float* r2wB = (const float*)d_in[19];
    const float* r2s  = (const float*)d_in[20];
    const float* r3pg = (const float*)d_in[21];
    const float* r3pb = (const float*)d_in[22];
    const float* r3wA = (const float*)d_in[23];
    const float* r3g  = (const float*)d_in[24];
    const float* r3b  = (const float*)d_in[25];
    const float* r3wB = (const float*)d_in[26];
    const float* r3s  = (const float*)d_in[27];
    const float* pbg  = (const float*)d_in[28];
    const float* pbb  = (const float*)d_in[29];
    const float* wih_f = (const float*)d_in[30];
    const float* whh_f = (const float*)d_in[31];
    const float* bih_f = (const float*)d_in[32];
    const float* bhh_f = (const float*)d_in[33];
    const float* wih_b = (const float*)d_in[34];
    const float* whh_b = (const float*)d_in[35];
    const float* bih_b = (const float*)d_in[36];
    const float* bhh_b = (const float*)d_in[37];
    const float* clsw  = (const float*)d_in[38];
    const float* clsb  = (const float*)d_in[39];
    float* out = (float*)d_out;
    float* ws  = (float*)d_ws;

    // ---- workspace sizing (floats) ----
    // fixed: WTR 962560, P 508896, XM 508896, XP4 253952, FE 507904, WF 262144,
    //        XPT 2031616, HC 507904, A1-slack 32768
    const size_t FIXEDF = 5576640;
    // per-img: A1 510880 + C1p 128960 + A2 257920 + C2p 67456 + A3 101184
    //        + B1 508896 + B2 253952 + B3 95232 + XP3 23808 + A4 31744 + B4 31744
    const size_t PCF = 2011776;
    int NC = 0;
    const int cands[6] = {32,16,8,4,2,1};
    for (int i = 0; i < 6; ++i) {
        if ((FIXEDF + (size_t)cands[i]*PCF)*sizeof(float) <= ws_size) { NC = cands[i]; break; }
    }
    if (!NC) return;

    float* p = ws;
    unsigned short* WTR = (unsigned short*)p; p += 962560;
    float* P   = p; p += 508896;
    float* XM  = p; p += 508896;
    unsigned short* XP4 = (unsigned short*)p; p += 253952;
    float* FE  = p; p += 507904;
    unsigned short* WF = (unsigned short*)p; p += 262144;
    float* XPT = p; p += 2031616;
    float* HC  = p; p += 507904;
    unsigned short* A1  = (unsigned short*)p; p += (size_t)NC*510880 + 32768;  // + slack
    unsigned short* C1p = (unsigned short*)p; p += (size_t)NC*128960;
    unsigned short* A2  = (unsigned short*)p; p += (size_t)NC*257920;
    unsigned short* C2p = (unsigned short*)p; p += (size_t)NC*67456;
    unsigned short* A3  = (unsigned short*)p; p += (size_t)NC*101184;
    unsigned short* B1  = (unsigned short*)p; p += (size_t)NC*508896;
    unsigned short* B2  = (unsigned short*)p; p += (size_t)NC*253952;
    unsigned short* B3  = (unsigned short*)p; p += (size_t)NC*95232;
    unsigned short* XP3 = (unsigned short*)p; p += (size_t)NC*23808;
    unsigned short* A4  = (unsigned short*)p; p += (size_t)NC*31744;
    unsigned short* B4  = (unsigned short*)p; p += (size_t)NC*31744;

    unsigned short* w2T  = WTR + 0;
    unsigned short* r1AT = WTR + 36864;
    unsigned short* r1BT = WTR + 110592;
    unsigned short* r1ST = WTR + 258048;
    unsigned short* r2AT = WTR + 266240;
    unsigned short* r2BT = WTR + 487424;
    unsigned short* r2ST = WTR + 819200;
    unsigned short* r3AT = WTR + 843776;
    unsigned short* r3BT = WTR + 1286144;
    unsigned short* r3ST = WTR + 1875968;

    auto cdiv = [](int a, int b){ return (a + b - 1) / b; };

    // ---- weight transforms ----
    wtrans9_kernel<<<cdiv(9*64*64,256),   256, 0, stream>>>(cbw2, w2T, 64, 64);
    wtrans9_kernel<<<cdiv(9*128*64,256),  256, 0, stream>>>(r1wA, r1AT, 128, 64);
    wtrans9_kernel<<<cdiv(9*128*128,256), 256, 0, stream>>>(r1wB, r1BT, 128, 128);
    wtrans1_kernel<<<cdiv(128*64,256),    256, 0, stream>>>(r1s, r1ST, 128*64);
    wtrans9_kernel<<<cdiv(9*192*128,256), 256, 0, stream>>>(r2wA, r2AT, 192, 128);
    wtrans9_kernel<<<cdiv(9*192*192,256), 256, 0, stream>>>(r2wB, r2BT, 192, 192);
    wtrans1_kernel<<<cdiv(192*128,256),   256, 0, stream>>>(r2s, r2ST, 192*128);
    wtrans9_kernel<<<cdiv(9*256*192,256), 256, 0, stream>>>(r3wA, r3AT, 256, 192);
    wtrans9_kernel<<<cdiv(9*256*256,256), 256, 0, stream>>>(r3wB, r3BT, 256, 256);
    wtrans1_kernel<<<cdiv(256*192,256),   256, 0, stream>>>(r3s, r3ST, 256*192);
    whh_frag_kernel<<<1024, 256, 0, stream>>>(whh_f, WF);
    whh_frag_kernel<<<1024, 256, 0, stream>>>(whh_b, WF + 262144);

    // ---- frontend mask ----
    mask_partial_kernel<<<dim3(63, 32), 256, 0, stream>>>(fW, fB, P);
    mask_finalize_apply<<<63, 256, 0, stream>>>(P, x, XM);

    // ---- zero the padded staging region (halo columns stay zero forever) ----
    hipMemsetAsync(A1, 0, ((size_t)NC*1066400 + 32768)*sizeof(float), stream);

    // ---- conv stack, chunked over batch ----
    for (int c0 = 0; c0 < 32; c0 += NC) {
        const float* xmc = XM + (size_t)c0*15903;
        // conv1: 1->64, out A1 padded [31][515][64]
        conv1_kernel<<<dim3(63, 1, NC), 256, 0, stream>>>(xmc, cbw1, cbg, cbb, A1);
        // conv2: 64->64, main tiles (w 0..511) + remainder (w 512)
        conv_row_kernel<64,8,0><<<dim3(4*31, 1, NC), 256, 0, stream>>>(
            A1, w2T, nullptr, nullptr, B1, 515, 513, 4, 0, 0, 513, 0, 64, r1pg, r1pb);
        conv_row_kernel<64,1,0><<<dim3(31, 1, NC), 256, 0, stream>>>(
            A1, w2T, nullptr, nullptr, B1, 515, 513, 1, 512, 0, 513, 0, 64, r1pg, r1pb);
        // pool 513->128 -> C1p padded [31][130][64]
        pool_nhwc_kernel<<<cdiv(NC*31*128*8,256), 256, 0, stream>>>(B1, C1p, 513, 128, 130, 1, 64, NC*31*128*8);
        // r1A: 64->128 -> A2 padded [31][130][128]
        conv_row_kernel<64,8,0><<<dim3(31, 2, NC), 256, 0, stream>>>(
            C1p, r1AT, nullptr, nullptr, A2, 130, 128, 1, 0, 0, 130, 1, 128, r1g, r1b);
        // r1B + shortcut -> B2 unpadded [31][128][128]
        conv_row_kernel<128,8,64><<<dim3(31, 2, NC), 256, 0, stream>>>(
            A2, r1BT, C1p, r1ST, B2, 130, 128, 1, 0, 130, 128, 0, 128, r2pg, r2pb);
        // pool 128->32 -> C2p padded [31][34][128]
        pool_nhwc_kernel<<<cdiv(NC*31*32*16,256), 256, 0, stream>>>(B2, C2p, 128, 32, 34, 1, 128, NC*31*32*16);
        // r2A: 128->192 -> A3 padded [31][34][192]
        conv_row_kernel<128,2,0><<<dim3(31, 3, NC), 256, 0, stream>>>(
            C2p, r2AT, nullptr, nullptr, A3, 34, 32, 1, 0, 0, 34, 1, 192, r2g, r2b);
        // r2B + shortcut -> B3 unpadded [31][32][192]
        conv_row_kernel<192,2,128><<<dim3(31, 3, NC), 256, 0, stream>>>(
            A3, r2BT, C2p, r2ST, B3, 34, 32, 1, 0, 34, 32, 0, 192, r3pg, r3pb);
        // pool 32->8 -> XP3 unpadded
        pool_nhwc_kernel<<<cdiv(NC*31*8*24,256), 256, 0, stream>>>(B3, XP3, 32, 8, 8, 0, 192, NC*31*8*24);
        // r3 (W=8): generic kernel
        conv_mfma_kernel<<<dim3(4, 4, NC), 256, 0, stream>>>(
            XP3, r3AT, nullptr, nullptr, A4, 31, 8, 192, 0, 256, r3g, r3b);
        conv_mfma_kernel<<<dim3(4, 4, NC), 256, 0, stream>>>(
            A4, r3BT, XP3, r3ST, B4, 31, 8, 256, 192, 256, pbg, pbb);
        // pool 8->2 -> XP4 slice
        pool_nhwc_kernel<<<cdiv(NC*31*2*32,256), 256, 0, stream>>>(
            B4, XP4 + (size_t)c0*15872, 8, 2, 2, 0, 256, NC*31*2*32);
    }

    // feats (32,31,512) fp32
    feats_kernel<<<1984, 256, 0, stream>>>(XP4, FE);

    // LSTM input projections -> xpT [d][t][b][j]
    gemm_bias_kernel<1><<<dim3(31, 16), 256, 0, stream>>>(FE, wih_f, bih_f, bhh_f, XPT,           992, 1024, 512);
    gemm_bias_kernel<1><<<dim3(31, 16), 256, 0, stream>>>(FE, wih_b, bih_b, bhh_b, XPT + 1015808, 992, 1024, 512);

    // fused bidirectional scan (4 blocks: dir x batch-half)
    lstm_scan_mfma<<<4, 1024, 0, stream>>>(XPT, WF, HC);

    // classifier -> d_out (32,31,722)
    gemm_bias_kernel<0><<<dim3(31, 12), 256, 0, stream>>>(HC, clsw, clsb, nullptr, out, 992, 722, 512);
}

// Round 9
// 1986.599 us; speedup vs baseline: 1.0400x; 1.0382x over previous
//
#include <hip/hip_runtime.h>
#include <hip/hip_bf16.h>
#include <math.h>

#define RSQ 0.99999500003749969f   // 1/sqrt(1+1e-5)
#define SLOPE 0.01f

typedef __attribute__((ext_vector_type(8))) short short8;
typedef __attribute__((ext_vector_type(4))) float f32x4;

__device__ __forceinline__ float sigmoidf_(float x){ return 1.0f/(1.0f+expf(-x)); }

__device__ __forceinline__ unsigned short f2bf(float f){
    unsigned u = __float_as_uint(f);
    u += 0x7fff + ((u >> 16) & 1);      // RNE
    return (unsigned short)(u >> 16);
}
__device__ __forceinline__ float bf2f(unsigned short s){
    return __uint_as_float(((unsigned)s) << 16);
}

// ---------------- mask: prod_k cos(fW*rng + fB) ----------------
__global__ void mask_partial_kernel(const float* __restrict__ fW, const float* __restrict__ fB,
                                    float* __restrict__ partial)
{
    int p = blockIdx.x*256 + threadIdx.x;   // 0..15902
    if (p >= 15903) return;
    int w = p % 513;
    float r = (float)(w + 1);
    int k0 = blockIdx.y * 32;
    float prod = 1.0f;
    for (int k = k0; k < k0 + 32; ++k) {
        float a = fW[(size_t)k*15903 + p] * r + fB[(size_t)k*15903 + p];
        prod *= cosf(a);
    }
    partial[blockIdx.y*15903 + p] = prod;
}

__global__ void mask_finalize_apply(const float* __restrict__ partial, const float* __restrict__ x,
                                    float* __restrict__ xm)
{
    int p = blockIdx.x*256 + threadIdx.x;
    if (p >= 15903) return;
    float m = 1.0f;
    #pragma unroll
    for (int c = 0; c < 32; ++c) m *= partial[c*15903 + p];
    for (int n = 0; n < 32; ++n)
        xm[(size_t)n*15903 + p] = x[(size_t)n*15903 + p] * m;
}

// ---------------- weight transforms ----------------
__global__ void wtrans9_kernel(const float* __restrict__ w, unsigned short* __restrict__ o,
                               int Cout, int Cin)
{
    int idx = blockIdx.x*256 + threadIdx.x;
    int cc = Cout*Cin;
    if (idx >= 9*cc) return;
    int tap = idx / cc;
    int r = idx - tap*cc;
    int co = r / Cin, ci = r - co*Cin;
    int kh = tap/3, kw = tap - kh*3;
    o[idx] = f2bf(w[((size_t)(co*Cin + ci)*3 + kh)*3 + kw]);
}
__global__ void wtrans1_kernel(const float* __restrict__ w, unsigned short* __restrict__ o, int total)
{
    int idx = blockIdx.x*256 + threadIdx.x;
    if (idx < total) o[idx] = f2bf(w[idx]);
}

// whh (1024,256) fp32 -> MFMA-fragment-contiguous bf16
__global__ void whh_frag_kernel(const float* __restrict__ whh, unsigned short* __restrict__ out)
{
    int tid = blockIdx.x*256 + threadIdx.x;  // 262144 exact
    int e    = tid & 7;
    int lane = (tid >> 3) & 63;
    int kc   = (tid >> 9) & 7;
    int u0   = (tid >> 12) & 15;
    int g    = tid >> 16;
    int j = (g << 8) + (u0 << 4) + (lane & 15);
    int k = (kc << 5) + ((lane >> 4) << 3) + e;
    out[tid] = f2bf(whh[(size_t)j*256 + k]);
}

// ---------------- conv1: Cin=1 direct, fp32 in -> bf16 NHWC out (padded stride 515) ----------------
__launch_bounds__(256)
__global__ void conv1_kernel(const float* __restrict__ xm, const float* __restrict__ w1,
                             const float* __restrict__ g, const float* __restrict__ b,
                             unsigned short* __restrict__ O)
{
    __shared__ float wl[576];
    __shared__ float sg[64], sb[64];
    int tid = threadIdx.x;
    if (tid < 64) { sg[tid] = g[tid]*RSQ; sb[tid] = b[tid]; }
    for (int i = tid; i < 576; i += 256) wl[i] = w1[i];
    __syncthreads();
    int px = blockIdx.x*256 + tid;
    int n = blockIdx.z;
    if (px >= 15903) return;
    int h = px / 513, w = px - h*513;
    const float* xp = xm + (size_t)n*15903;
    float v[9];
    #pragma unroll
    for (int dh = 0; dh < 3; ++dh)
      #pragma unroll
      for (int dw = 0; dw < 3; ++dw) {
        int hh = h+dh-1, ww = w+dw-1;
        bool ok = ((unsigned)hh < 31u) && ((unsigned)ww < 513u);
        v[dh*3+dw] = ok ? xp[hh*513 + ww] : 0.f;
      }
    unsigned short* op = O + (((size_t)(n*31 + h))*515 + (w + 1))*64;
    #pragma unroll
    for (int c8 = 0; c8 < 8; ++c8) {
        unsigned tmp[8];
        #pragma unroll
        for (int j = 0; j < 8; ++j) {
            int co = c8*8 + j;
            const float* wr = &wl[co*9];
            float a = 0.f;
            #pragma unroll
            for (int t2 = 0; t2 < 9; ++t2) a += wr[t2]*v[t2];
            a = a*sg[co] + sb[co];
            a = (a >= 0.f) ? a : SLOPE*a;
            tmp[j] = f2bf(a);
        }
        uint4 pk;
        pk.x = tmp[0] | (tmp[1]<<16);
        pk.y = tmp[2] | (tmp[3]<<16);
        pk.z = tmp[4] | (tmp[5]<<16);
        pk.w = tmp[6] | (tmp[7]<<16);
        *(uint4*)(op + c8*8) = pk;
    }
}

// ---------------- padded row-tiled implicit-GEMM 3x3 conv (+1x1 shortcut) via MFMA ----------------
// POOL=1: epilogue fuses bn+lrelu+maxpool(1,4); O gets pooled cols (stride WpO, offset OOFF).
template<int CIN, int TPX, int CS, int POOL>
__launch_bounds__(256, 2)
__global__ void conv_row_kernel(const unsigned short* __restrict__ X,
                                const unsigned short* __restrict__ W9,
                                const unsigned short* __restrict__ Xs,
                                const unsigned short* __restrict__ Ws,
                                unsigned short* __restrict__ O,
                                int Wp, int Wv, int WT, int W0OFF, int WpS,
                                int WpO, int OOFF, int Cout,
                                const float* __restrict__ g, const float* __restrict__ b)
{
    const int lane = threadIdx.x & 63;
    const int wave = threadIdx.x >> 6;
    const int cob  = blockIdx.y * 64 + wave * 16;
    const int n  = blockIdx.z;
    const int wt = blockIdx.x % WT;
    const int h  = blockIdx.x / WT;
    const int w0 = W0OFF + wt * (TPX*16);
    const int l15 = lane & 15;
    const int kl = (lane >> 4) * 8;

    f32x4 acc[TPX] = {};

    #pragma unroll
    for (int dh = 0; dh < 3; ++dh) {
        int hh = h - 1 + dh;
        if ((unsigned)hh >= 31u) continue;                  // wave-uniform
        const unsigned short* rp = X + ((size_t)(n*31 + hh) * Wp)*CIN;
        const unsigned short* bbase[TPX];
        #pragma unroll
        for (int t = 0; t < TPX; ++t)
            bbase[t] = rp + (size_t)(w0 + t*16 + l15)*CIN + kl;
        #pragma unroll
        for (int dw = 0; dw < 3; ++dw) {
            const unsigned short* ap = W9 + ((size_t)(dh*3+dw)*Cout + cob + l15)*CIN + kl;
            #pragma unroll
            for (int k0 = 0; k0 < CIN; k0 += 32) {
                short8 a = *(const short8*)(ap + k0);
                #pragma unroll
                for (int t = 0; t < TPX; ++t) {
                    short8 bv = *(const short8*)(bbase[t] + dw*CIN + k0);
                    acc[t] = __builtin_amdgcn_mfma_f32_16x16x32_bf16(a, bv, acc[t], 0, 0, 0);
                }
            }
        }
    }

    if (CS > 0) {   // fused 1x1 shortcut from padded Xs (center tap -> col +1)
        const unsigned short* rs = Xs + ((size_t)(n*31 + h) * WpS)*CS;
        const unsigned short* ap2 = Ws + (size_t)(cob + l15)*CS + kl;
        const unsigned short* sbase[TPX];
        #pragma unroll
        for (int t = 0; t < TPX; ++t)
            sbase[t] = rs + (size_t)(w0 + t*16 + l15 + 1)*CS + kl;
        #pragma unroll
        for (int k0 = 0; k0 < (CS > 0 ? CS : 32); k0 += 32) {
            short8 a = *(const short8*)(ap2 + k0);
            #pragma unroll
            for (int t = 0; t < TPX; ++t) {
                short8 bv = *(const short8*)(sbase[t] + k0);
                acc[t] = __builtin_amdgcn_mfma_f32_16x16x32_bf16(a, bv, acc[t], 0, 0, 0);
            }
        }
    }

    // epilogue: bn + lrelu (+ optional maxpool4) -> bf16
    int cb = cob + (lane >> 4)*4;
    float s0 = g[cb+0]*RSQ, s1 = g[cb+1]*RSQ, s2 = g[cb+2]*RSQ, s3 = g[cb+3]*RSQ;
    float o0 = b[cb+0], o1 = b[cb+1], o2 = b[cb+2], o3 = b[cb+3];
    #pragma unroll
    for (int t = 0; t < TPX; ++t) {
        float v0 = acc[t][0]*s0 + o0; v0 = (v0 >= 0.f) ? v0 : SLOPE*v0;
        float v1 = acc[t][1]*s1 + o1; v1 = (v1 >= 0.f) ? v1 : SLOPE*v1;
        float v2 = acc[t][2]*s2 + o2; v2 = (v2 >= 0.f) ? v2 : SLOPE*v2;
        float v3 = acc[t][3]*s3 + o3; v3 = (v3 >= 0.f) ? v3 : SLOPE*v3;
        if (POOL) {
            v0 = fmaxf(v0, __shfl_xor(v0, 1)); v0 = fmaxf(v0, __shfl_xor(v0, 2));
            v1 = fmaxf(v1, __shfl_xor(v1, 1)); v1 = fmaxf(v1, __shfl_xor(v1, 2));
            v2 = fmaxf(v2, __shfl_xor(v2, 1)); v2 = fmaxf(v2, __shfl_xor(v2, 2));
            v3 = fmaxf(v3, __shfl_xor(v3, 1)); v3 = fmaxf(v3, __shfl_xor(v3, 2));
            if ((l15 & 3) == 0) {
                int pw = (w0 + t*16 + l15) >> 2;
                uint2 pk;
                pk.x = (unsigned)f2bf(v0) | ((unsigned)f2bf(v1) << 16);
                pk.y = (unsigned)f2bf(v2) | ((unsigned)f2bf(v3) << 16);
                *(uint2*)(O + (((size_t)(n*31 + h))*WpO + pw + OOFF)*Cout + cb) = pk;
            }
        } else {
            int w = w0 + t*16 + l15;
            if (w < Wv) {
                uint2 pk;
                pk.x = (unsigned)f2bf(v0) | ((unsigned)f2bf(v1) << 16);
                pk.y = (unsigned)f2bf(v2) | ((unsigned)f2bf(v3) << 16);
                *(uint2*)(O + (((size_t)(n*31 + h))*WpO + w + OOFF)*Cout + cb) = pk;
            }
        }
    }
}

// ---------------- generic px-tiled conv (kept for W=8 layers) ----------------
__launch_bounds__(256)
__global__ void conv_mfma_kernel(const unsigned short* __restrict__ X,
                                 const unsigned short* __restrict__ W9,
                                 const unsigned short* __restrict__ Xs,
                                 const unsigned short* __restrict__ Ws,
                                 unsigned short* __restrict__ O,
                                 int H, int W, int Cin, int Cs, int Cout,
                                 const float* __restrict__ g, const float* __restrict__ b)
{
    const int HW = H * W;
    const int lane = threadIdx.x & 63;
    const int wave = threadIdx.x >> 6;
    const int co64 = blockIdx.y * 64 + wave * 16;
    const int n = blockIdx.z;
    const int px0 = blockIdx.x * 64;
    const int l15 = lane & 15;
    const int kl = (lane >> 4) * 8;
    const short8 zf = {0,0,0,0,0,0,0,0};

    int hh_[4], ww_[4]; bool pv[4];
    #pragma unroll
    for (int t = 0; t < 4; ++t) {
        int px = px0 + t*16 + l15;
        pv[t] = px < HW;
        int pc = pv[t] ? px : 0;
        hh_[t] = pc / W;
        ww_[t] = pc - hh_[t]*W;
    }

    const unsigned short* Xn = X + (size_t)n * HW * Cin;
    f32x4 acc0 = {0,0,0,0}, acc1 = {0,0,0,0}, acc2 = {0,0,0,0}, acc3 = {0,0,0,0};

    for (int tap = 0; tap < 9; ++tap) {
        int dh = tap/3 - 1, dw = tap - (tap/3)*3 - 1;
        const short8* ap = (const short8*)(W9 + ((size_t)tap*Cout + co64 + l15)*Cin + kl);
        const short8* bp[4]; bool v[4];
        #pragma unroll
        for (int t = 0; t < 4; ++t) {
            int hh = hh_[t] + dh, ww = ww_[t] + dw;
            v[t] = pv[t] && ((unsigned)hh < (unsigned)H) && ((unsigned)ww < (unsigned)W);
            int p2 = v[t] ? (hh*W + ww) : 0;
            bp[t] = (const short8*)(Xn + (size_t)p2*Cin + kl);
        }
        for (int k0 = 0; k0 < Cin; k0 += 32) {
            int ko = k0 >> 3;
            short8 a  = ap[ko];
            short8 b0 = v[0] ? bp[0][ko] : zf;
            short8 b1 = v[1] ? bp[1][ko] : zf;
            short8 b2 = v[2] ? bp[2][ko] : zf;
            short8 b3 = v[3] ? bp[3][ko] : zf;
            acc0 = __builtin_amdgcn_mfma_f32_16x16x32_bf16(a, b0, acc0, 0, 0, 0);
            acc1 = __builtin_amdgcn_mfma_f32_16x16x32_bf16(a, b1, acc1, 0, 0, 0);
            acc2 = __builtin_amdgcn_mfma_f32_16x16x32_bf16(a, b2, acc2, 0, 0, 0);
            acc3 = __builtin_amdgcn_mfma_f32_16x16x32_bf16(a, b3, acc3, 0, 0, 0);
        }
    }

    if (Ws) {
        const unsigned short* X2n = Xs + (size_t)n * HW * Cs;
        const short8* ap = (const short8*)(Ws + ((size_t)(co64 + l15))*Cs + kl);
        const short8* bp[4];
        #pragma unroll
        for (int t = 0; t < 4; ++t) {
            int p2 = pv[t] ? (hh_[t]*W + ww_[t]) : 0;
            bp[t] = (const short8*)(X2n + (size_t)p2*Cs + kl);
        }
        for (int k0 = 0; k0 < Cs; k0 += 32) {
            int ko = k0 >> 3;
            short8 a  = ap[ko];
            short8 b0 = pv[0] ? bp[0][ko] : zf;
            short8 b1 = pv[1] ? bp[1][ko] : zf;
            short8 b2 = pv[2] ? bp[2][ko] : zf;
            short8 b3 = pv[3] ? bp[3][ko] : zf;
            acc0 = __builtin_amdgcn_mfma_f32_16x16x32_bf16(a, b0, acc0, 0, 0, 0);
            acc1 = __builtin_amdgcn_mfma_f32_16x16x32_bf16(a, b1, acc1, 0, 0, 0);
            acc2 = __builtin_amdgcn_mfma_f32_16x16x32_bf16(a, b2, acc2, 0, 0, 0);
            acc3 = __builtin_amdgcn_mfma_f32_16x16x32_bf16(a, b3, acc3, 0, 0, 0);
        }
    }

    int cb = co64 + (lane >> 4)*4;
    float s0 = g[cb+0]*RSQ, s1 = g[cb+1]*RSQ, s2 = g[cb+2]*RSQ, s3 = g[cb+3]*RSQ;
    float o0 = b[cb+0], o1 = b[cb+1], o2 = b[cb+2], o3 = b[cb+3];

#define EPI(ACC, T) do { \
    if (pv[T]) { \
        int px = px0 + (T)*16 + l15; \
        float v0 = ACC[0]*s0 + o0; v0 = (v0 >= 0.f) ? v0 : SLOPE*v0; \
        float v1 = ACC[1]*s1 + o1; v1 = (v1 >= 0.f) ? v1 : SLOPE*v1; \
        float v2 = ACC[2]*s2 + o2; v2 = (v2 >= 0.f) ? v2 : SLOPE*v2; \
        float v3 = ACC[3]*s3 + o3; v3 = (v3 >= 0.f) ? v3 : SLOPE*v3; \
        uint2 pk; \
        pk.x = (unsigned)f2bf(v0) | ((unsigned)f2bf(v1) << 16); \
        pk.y = (unsigned)f2bf(v2) | ((unsigned)f2bf(v3) << 16); \
        *(uint2*)(O + ((size_t)n*HW + px)*Cout + cb) = pk; \
    } \
} while(0)
    EPI(acc0, 0); EPI(acc1, 1); EPI(acc2, 2); EPI(acc3, 3);
#undef EPI
}

// ---------------- maxpool(1,4) VALID on NHWC bf16 (only for final 8->2) ----------------
__global__ void pool_nhwc_kernel(const unsigned short* __restrict__ in,
                                 unsigned short* __restrict__ out,
                                 int Win, int Wout, int WpO, int OOFF, int C, int total8)
{
    int idx = blockIdx.x*256 + threadIdx.x;
    if (idx >= total8) return;
    int c8 = idx % (C >> 3);
    int r = idx / (C >> 3);
    int w = r % Wout;
    int nh = r / Wout;
    const unsigned short* ip = in + (((size_t)nh*Win) + (size_t)w*4)*C + c8*8;
    float m0=-1e30f,m1=-1e30f,m2=-1e30f,m3=-1e30f,m4=-1e30f,m5=-1e30f,m6=-1e30f,m7=-1e30f;
    #pragma unroll
    for (int i = 0; i < 4; ++i) {
        uint4 u = *(const uint4*)(ip + (size_t)i*C);
        m0 = fmaxf(m0, bf2f((unsigned short)(u.x & 0xffff)));
        m1 = fmaxf(m1, bf2f((unsigned short)(u.x >> 16)));
        m2 = fmaxf(m2, bf2f((unsigned short)(u.y & 0xffff)));
        m3 = fmaxf(m3, bf2f((unsigned short)(u.y >> 16)));
        m4 = fmaxf(m4, bf2f((unsigned short)(u.z & 0xffff)));
        m5 = fmaxf(m5, bf2f((unsigned short)(u.z >> 16)));
        m6 = fmaxf(m6, bf2f((unsigned short)(u.w & 0xffff)));
        m7 = fmaxf(m7, bf2f((unsigned short)(u.w >> 16)));
    }
    uint4 ov;
    ov.x = (unsigned)f2bf(m0) | ((unsigned)f2bf(m1) << 16);
    ov.y = (unsigned)f2bf(m2) | ((unsigned)f2bf(m3) << 16);
    ov.z = (unsigned)f2bf(m4) | ((unsigned)f2bf(m5) << 16);
    ov.w = (unsigned)f2bf(m6) | ((unsigned)f2bf(m7) << 16);
    *(uint4*)(out + (((size_t)nh*WpO) + w + OOFF)*C + c8*8) = ov;
}

// ---------------- feats: [n][31][2][256] bf16 NHWC -> [n][31][512] fp32 ----------------
__global__ void feats_kernel(const unsigned short* __restrict__ p4, float* __restrict__ fe)
{
    int idx = blockIdx.x*256 + threadIdx.x;   // 507904
    int cw = idx & 511;
    int nh = idx >> 9;
    int c = cw >> 1, w = cw & 1;
    fe[idx] = bf2f(p4[((size_t)nh*2 + w)*256 + c]);
}

// ---------------- tiled SGEMM: C[M,N] = A[M,K] @ B[N,K]^T + bias(+bias2) ----------------
#define GM 32
#define GN 64
#define GK 32
template<int XPOSE>
__launch_bounds__(256)
__global__ void gemm_bias_kernel(const float* __restrict__ A, const float* __restrict__ B,
                                 const float* __restrict__ bias, const float* __restrict__ bias2,
                                 float* __restrict__ C, int M, int N, int K)
{
    __shared__ float As[GM][GK+1];
    __shared__ float Bs[GN][GK+1];
    int m0 = blockIdx.x*GM, n0 = blockIdx.y*GN;
    int tid = threadIdx.x;
    int mi = tid >> 4;
    int ni = (tid & 15) * 4;
    float acc[2][4] = {};

    for (int k0 = 0; k0 < K; k0 += GK) {
        for (int i = tid; i < GM*GK; i += 256) {
            int r = i >> 5, c = i & 31;
            int m = m0 + r;
            As[r][c] = (m < M) ? A[(size_t)m*K + k0 + c] : 0.f;
        }
        for (int i = tid; i < GN*GK; i += 256) {
            int r = i >> 5, c = i & 31;
            int n = n0 + r;
            Bs[r][c] = (n < N) ? B[(size_t)n*K + k0 + c] : 0.f;
        }
        __syncthreads();
        #pragma unroll
        for (int kk = 0; kk < GK; ++kk) {
            float a0 = As[mi][kk], a1 = As[mi+16][kk];
            float b0 = Bs[ni][kk], b1 = Bs[ni+1][kk], b2 = Bs[ni+2][kk], b3 = Bs[ni+3][kk];
            acc[0][0] += a0*b0; acc[0][1] += a0*b1; acc[0][2] += a0*b2; acc[0][3] += a0*b3;
            acc[1][0] += a1*b0; acc[1][1] += a1*b1; acc[1][2] += a1*b2; acc[1][3] += a1*b3;
        }
        __syncthreads();
    }
    #pragma unroll
    for (int r = 0; r < 2; ++r) {
        int m = m0 + mi + r*16;
        if (m >= M) continue;
        #pragma unroll
        for (int q = 0; q < 4; ++q) {
            int n = n0 + ni + q;
            if (n >= N) continue;
            float v = acc[r][q];
            if (bias)  v += bias[n];
            if (bias2) v += bias2[n];
            if (XPOSE) C[((size_t)(m % 31)*32 + (m / 31))*N + n] = v;
            else       C[(size_t)m*N + n] = v;
        }
    }
}

// ---------------- LSTM scan via MFMA: 4 blocks = (dir x batch-half), 1024 thr ----------------
// explicit 4-group software pipeline for the whh stream (load->use distance = 3 kc-blocks)
__launch_bounds__(1024, 4)
__global__ void lstm_scan_mfma(const float* __restrict__ xpT,
                               const unsigned short* __restrict__ wf,
                               float* __restrict__ hcat)
{
    const int d  = blockIdx.x >> 1;
    const int bh = blockIdx.x & 1;
    const int tid = threadIdx.x;
    const int u0 = tid >> 6;
    const int lane = tid & 63;
    const int l15 = lane & 15;
    const int q = lane >> 4;

    __shared__ unsigned short hbuf[2][4096];
    ((int4*)hbuf)[tid] = make_int4(0,0,0,0);
    __syncthreads();

    const unsigned short* wfd = wf + (size_t)d*262144;
    const float* xpd = xpT + (size_t)d*992*1024 + (size_t)bh*16*1024;
    const unsigned short* wp = wfd + u0*4096 + lane*8;

    float c0=0.f, c1=0.f, c2=0.f, c3=0.f;
    const int ubase = u0*16 + q*4;
    const int rb = l15*512 + q*16;
    const int xr = (l15&7)<<4;

#define WLD(kc,g) (*(const short8*)(wp + (kc)*512 + (g)*65536))
#define HRD(kc)   (*(const short8*)(hb + ((rb + (kc)*64) ^ xr)))
#define MF(w_,h_,a_) a_ = __builtin_amdgcn_mfma_f32_16x16x32_bf16(w_, h_, a_, 0, 0, 0)

    for (int s = 0; s < 31; ++s) {
        const int t = d ? (30 - s) : s;
        const int cur = s & 1, nxt = cur ^ 1;
        const float* xb = xpd + (size_t)t*32768 + (size_t)l15*1024;
        float4 xi = *(const float4*)(xb + ubase);
        float4 xf = *(const float4*)(xb + 256 + ubase);
        float4 xg = *(const float4*)(xb + 512 + ubase);
        float4 xo = *(const float4*)(xb + 768 + ubase);

        const char* hb = (const char*)hbuf[cur];
        f32x4 a0={0,0,0,0}, a1={0,0,0,0}, a2={0,0,0,0}, a3={0,0,0,0};

        short8 wA0=WLD(0,0), wA1=WLD(0,1), wA2=WLD(0,2), wA3=WLD(0,3);
        short8 wB0=WLD(1,0), wB1=WLD(1,1), wB2=WLD(1,2), wB3=WLD(1,3);
        short8 wC0=WLD(2,0), wC1=WLD(2,1), wC2=WLD(2,2), wC3=WLD(2,3);
        short8 wD0=WLD(3,0), wD1=WLD(3,1), wD2=WLD(3,2), wD3=WLD(3,3);

        { short8 h=HRD(0); MF(wA0,h,a0); MF(wA1,h,a1); MF(wA2,h,a2); MF(wA3,h,a3); }
        wA0=WLD(4,0); wA1=WLD(4,1); wA2=WLD(4,2); wA3=WLD(4,3);
        { short8 h=HRD(1); MF(wB0,h,a0); MF(wB1,h,a1); MF(wB2,h,a2); MF(wB3,h,a3); }
        wB0=WLD(5,0); wB1=WLD(5,1); wB2=WLD(5,2); wB3=WLD(5,3);
        { short8 h=HRD(2); MF(wC0,h,a0); MF(wC1,h,a1); MF(wC2,h,a2); MF(wC3,h,a3); }
        wC0=WLD(6,0); wC1=WLD(6,1); wC2=WLD(6,2); wC3=WLD(6,3);
        { short8 h=HRD(3); MF(wD0,h,a0); MF(wD1,h,a1); MF(wD2,h,a2); MF(wD3,h,a3); }
        wD0=WLD(7,0); wD1=WLD(7,1); wD2=WLD(7,2); wD3=WLD(7,3);
        { short8 h=HRD(4); MF(wA0,h,a0); MF(wA1,h,a1); MF(wA2,h,a2); MF(wA3,h,a3); }
        { short8 h=HRD(5); MF(wB0,h,a0); MF(wB1,h,a1); MF(wB2,h,a2); MF(wB3,h,a3); }
        { short8 h=HRD(6); MF(wC0,h,a0); MF(wC1,h,a1); MF(wC2,h,a2); MF(wC3,h,a3); }
        { short8 h=HRD(7); MF(wD0,h,a0); MF(wD1,h,a1); MF(wD2,h,a2); MF(wD3,h,a3); }

        float hv0, hv1, hv2, hv3;
        { float gi=a0[0]+xi.x, gf=a1[0]+xf.x, gg=a2[0]+xg.x, go=a3[0]+xo.x;
          float cn = sigmoidf_(gf)*c0 + sigmoidf_(gi)*tanhf(gg); c0 = cn; hv0 = sigmoidf_(go)*tanhf(cn); }
        { float gi=a0[1]+xi.y, gf=a1[1]+xf.y, gg=a2[1]+xg.y, go=a3[1]+xo.y;
          float cn = sigmoidf_(gf)*c1 + sigmoidf_(gi)*tanhf(gg); c1 = cn; hv1 = sigmoidf_(go)*tanhf(cn); }
        { float gi=a0[2]+xi.z, gf=a1[2]+xf.z, gg=a2[2]+xg.z, go=a3[2]+xo.z;
          float cn = sigmoidf_(gf)*c2 + sigmoidf_(gi)*tanhf(gg); c2 = cn; hv2 = sigmoidf_(go)*tanhf(cn); }
        { float gi=a0[3]+xi.w, gf=a1[3]+xf.w, gg=a2[3]+xg.w, go=a3[3]+xo.w;
          float cn = sigmoidf_(gf)*c3 + sigmoidf_(gi)*tanhf(gg); c3 = cn; hv3 = sigmoidf_(go)*tanhf(cn); }

        short4 hp;
        hp.x = (short)f2bf(hv0); hp.y = (short)f2bf(hv1);
        hp.z = (short)f2bf(hv2); hp.w = (short)f2bf(hv3);
        *(short4*)((char*)hbuf[nxt] + ((l15*512 + ubase*2) ^ xr)) = hp;
        int bg = bh*16 + l15;
        *(float4*)(&hcat[((size_t)bg*31 + t)*512 + (size_t)d*256 + ubase]) =
            make_float4(hv0, hv1, hv2, hv3);

        __syncthreads();
    }
#undef WLD
#undef HRD
#undef MF
}

extern "C" void kernel_launch(void* const* d_in, const int* in_sizes, int n_in,
                              void* d_out, int out_size, void* d_ws, size_t ws_size,
                              hipStream_t stream)
{
    const float* x    = (const float*)d_in[0];
    const float* fW   = (const float*)d_in[1];
    const float* fB   = (const float*)d_in[2];
    const float* cbw1 = (const float*)d_in[3];
    const float* cbg  = (const float*)d_in[4];
    const float* cbb  = (const float*)d_in[5];
    const float* cbw2 = (const float*)d_in[6];
    const float* r1pg = (const float*)d_in[7];
    const float* r1pb = (const float*)d_in[8];
    const float* r1wA = (const float*)d_in[9];
    const float* r1g  = (const float*)d_in[10];
    const float* r1b  = (const float*)d_in[11];
    const float* r1wB = (const float*)d_in[12];
    const float* r1s  = (const float*)d_in[13];
    const float* r2pg = (const float*)d_in[14];
    const float* r2pb = (const float*)d_in[15];
    const float* r2wA = (const float*)d_in[16];
    const float* r2g  = (const float*)d_in[17];
    const float* r2b  = (const float*)d_in[18];
    const float* r2wB = (const float*)d_in[19];
    const float* r2s  = (const float*)d_in[20];
    const float* r3pg = (const float*)d_in[21];
    const float* r3pb = (const float*)d_in[22];
    const float* r3wA = (const float*)d_in[23];
    const float* r3g  = (const float*)d_in[24];
    const float* r3b  = (const float*)d_in[25];
    const float* r3wB = (const float*)d_in[26];
    const float* r3s  = (const float*)d_in[27];
    const float* pbg  = (const float*)d_in[28];
    const float* pbb  = (const float*)d_in[29];
    const float* wih_f = (const float*)d_in[30];
    const float* whh_f = (const float*)d_in[31];
    const float* bih_f = (const float*)d_in[32];
    const float* bhh_f = (const float*)d_in[33];
    const float* wih_b = (const float*)d_in[34];
    const float* whh_b = (const float*)d_in[35];
    const float* bih_b = (const float*)d_in[36];
    const float* bhh_b = (const float*)d_in[37];
    const float* clsw  = (const float*)d_in[38];
    const float* clsb  = (const float*)d_in[39];
    float* out = (float*)d_out;
    float* ws  = (float*)d_ws;

    // ---- workspace sizing ----
    // fixed floats: WTR 962560 + P 508896 + XM 508896 + XP4 253952 + FE 507904
    //             + WF 262144 + XPT 2031616 + HC 507904 = 5543872
    const size_t FIXEDF = 5543872;
    // per-img shorts: padded A1 1021760 + C1p 257920 + A2 515840 + C2p 134912 + A3 202368
    //               + XP3 47616 + A4 63488 + B4 63488 = 2307392 shorts = 1153696 floats
    const size_t PADDED_SHORTS = 2132800;   // per img, memset region
    const size_t PCF = 1153696;
    int NC = 0;
    const int cands[6] = {32,16,8,4,2,1};
    for (int i = 0; i < 6; ++i) {
        if ((FIXEDF + (size_t)cands[i]*PCF + 64)*sizeof(float) <= ws_size) { NC = cands[i]; break; }
    }
    if (!NC) return;

    float* p = ws;
    unsigned short* WTR = (unsigned short*)p; p += 962560;
    float* P   = p; p += 508896;
    float* XM  = p; p += 508896;
    unsigned short* XP4 = (unsigned short*)p; p += 253952;
    float* FE  = p; p += 507904;
    unsigned short* WF = (unsigned short*)p; p += 262144;
    float* XPT = p; p += 2031616;
    float* HC  = p; p += 507904;
    unsigned short* q = (unsigned short*)p;
    unsigned short* A1  = q; q += (size_t)NC*1021760;
    unsigned short* C1p = q; q += (size_t)NC*257920;
    unsigned short* A2  = q; q += (size_t)NC*515840;
    unsigned short* C2p = q; q += (size_t)NC*134912;
    unsigned short* A3  = q; q += (size_t)NC*202368;
    unsigned short* XP3 = q; q += (size_t)NC*47616;
    unsigned short* A4  = q; q += (size_t)NC*63488;
    unsigned short* B4  = q; q += (size_t)NC*63488;

    unsigned short* w2T  = WTR + 0;
    unsigned short* r1AT = WTR + 36864;
    unsigned short* r1BT = WTR + 110592;
    unsigned short* r1ST = WTR + 258048;
    unsigned short* r2AT = WTR + 266240;
    unsigned short* r2BT = WTR + 487424;
    unsigned short* r2ST = WTR + 819200;
    unsigned short* r3AT = WTR + 843776;
    unsigned short* r3BT = WTR + 1286144;
    unsigned short* r3ST = WTR + 1875968;

    auto cdiv = [](int a, int b){ return (a + b - 1) / b; };

    // ---- weight transforms ----
    wtrans9_kernel<<<cdiv(9*64*64,256),   256, 0, stream>>>(cbw2, w2T, 64, 64);
    wtrans9_kernel<<<cdiv(9*128*64,256),  256, 0, stream>>>(r1wA, r1AT, 128, 64);
    wtrans9_kernel<<<cdiv(9*128*128,256), 256, 0, stream>>>(r1wB, r1BT, 128, 128);
    wtrans1_kernel<<<cdiv(128*64,256),    256, 0, stream>>>(r1s, r1ST, 128*64);
    wtrans9_kernel<<<cdiv(9*192*128,256), 256, 0, stream>>>(r2wA, r2AT, 192, 128);
    wtrans9_kernel<<<cdiv(9*192*192,256), 256, 0, stream>>>(r2wB, r2BT, 192, 192);
    wtrans1_kernel<<<cdiv(192*128,256),   256, 0, stream>>>(r2s, r2ST, 192*128);
    wtrans9_kernel<<<cdiv(9*256*192,256), 256, 0, stream>>>(r3wA, r3AT, 256, 192);
    wtrans9_kernel<<<cdiv(9*256*256,256), 256, 0, stream>>>(r3wB, r3BT, 256, 256);
    wtrans1_kernel<<<cdiv(256*192,256),   256, 0, stream>>>(r3s, r3ST, 256*192);
    whh_frag_kernel<<<1024, 256, 0, stream>>>(whh_f, WF);
    whh_frag_kernel<<<1024, 256, 0, stream>>>(whh_b, WF + 262144);

    // ---- frontend mask ----
    mask_partial_kernel<<<dim3(63, 32), 256, 0, stream>>>(fW, fB, P);
    mask_finalize_apply<<<63, 256, 0, stream>>>(P, x, XM);

    // ---- zero padded staging region (halos stay zero) ----
    hipMemsetAsync(A1, 0, (size_t)NC*PADDED_SHORTS*sizeof(unsigned short), stream);

    // ---- conv stack, chunked over batch ----
    for (int c0 = 0; c0 < 32; c0 += NC) {
        const float* xmc = XM + (size_t)c0*15903;
        // conv1: 1->64, out A1 padded [31][515][64]
        conv1_kernel<<<dim3(63, 1, NC), 256, 0, stream>>>(xmc, cbw1, cbg, cbb, A1);
        // conv2 + bn(r1pg,r1pb)+lrelu+pool4: 64->64, W 513->128, out C1p padded [31][130][64]
        conv_row_kernel<64,8,0,1><<<dim3(4*31, 1, NC), 256, 0, stream>>>(
            A1, w2T, nullptr, nullptr, C1p, 515, 513, 4, 0, 0, 130, 1, 64, r1pg, r1pb);
        // r1A: 64->128, out A2 padded [31][130][128]
        conv_row_kernel<64,8,0,0><<<dim3(31, 2, NC), 256, 0, stream>>>(
            C1p, r1AT, nullptr, nullptr, A2, 130, 128, 1, 0, 0, 130, 1, 128, r1g, r1b);
        // r1B + shortcut + bn(r2pg,r2pb)+lrelu+pool4: W 128->32, out C2p padded [31][34][128]
        conv_row_kernel<128,8,64,1><<<dim3(31, 2, NC), 256, 0, stream>>>(
            A2, r1BT, C1p, r1ST, C2p, 130, 128, 1, 0, 130, 34, 1, 128, r2pg, r2pb);
        // r2A: 128->192, out A3 padded [31][34][192]
        conv_row_kernel<128,2,0,0><<<dim3(31, 3, NC), 256, 0, stream>>>(
            C2p, r2AT, nullptr, nullptr, A3, 34, 32, 1, 0, 0, 34, 1, 192, r2g, r2b);
        // r2B + shortcut + bn(r3pg,r3pb)+lrelu+pool4: W 32->8, out XP3 unpadded [31][8][192]
        conv_row_kernel<192,2,128,1><<<dim3(31, 3, NC), 256, 0, stream>>>(
            A3, r2BT, C2p, r2ST, XP3, 34, 32, 1, 0, 34, 8, 0, 192, r3pg, r3pb);
        // r3 (W=8): generic kernels
        conv_mfma_kernel<<<dim3(4, 4, NC), 256, 0, stream>>>(
            XP3, r3AT, nullptr, nullptr, A4, 31, 8, 192, 0, 256, r3g, r3b);
        conv_mfma_kernel<<<dim3(4, 4, NC), 256, 0, stream>>>(
            A4, r3BT, XP3, r3ST, B4, 31, 8, 256, 192, 256, pbg, pbb);
        // final pool 8->2 -> XP4 slice
        pool_nhwc_kernel<<<cdiv(NC*31*2*32,256), 256, 0, stream>>>(
            B4, XP4 + (size_t)c0*15872, 8, 2, 2, 0, 256, NC*31*2*32);
    }

    // feats (32,31,512) fp32
    feats_kernel<<<1984, 256, 0, stream>>>(XP4, FE);

    // LSTM input projections -> xpT [d][t][b][j]
    gemm_bias_kernel<1><<<dim3(31, 16), 256, 0, stream>>>(FE, wih_f, bih_f, bhh_f, XPT,           992, 1024, 512);
    gemm_bias_kernel<1><<<dim3(31, 16), 256, 0, stream>>>(FE, wih_b, bih_b, bhh_b, XPT + 1015808, 992, 1024, 512);

    // fused bidirectional scan (4 blocks: dir x batch-half)
    lstm_scan_mfma<<<4, 1024, 0, stream>>>(XPT, WF, HC);

    // classifier -> d_out (32,31,722)
    gemm_bias_kernel<0><<<dim3(31, 12), 256, 0, stream>>>(HC, clsw, clsb, nullptr, out, 992, 722, 512);
}

// Round 10
// 1438.558 us; speedup vs baseline: 1.4362x; 1.3810x over previous
//
#include <hip/hip_runtime.h>
#include <hip/hip_bf16.h>
#include <math.h>

#define RSQ 0.99999500003749969f   // 1/sqrt(1+1e-5)
#define SLOPE 0.01f

typedef __attribute__((ext_vector_type(8))) short short8;
typedef __attribute__((ext_vector_type(4))) float f32x4;

__device__ __forceinline__ float sigmoidf_(float x){ return 1.0f/(1.0f+expf(-x)); }

__device__ __forceinline__ unsigned short f2bf(float f){
    unsigned u = __float_as_uint(f);
    u += 0x7fff + ((u >> 16) & 1);      // RNE
    return (unsigned short)(u >> 16);
}
__device__ __forceinline__ float bf2f(unsigned short s){
    return __uint_as_float(((unsigned)s) << 16);
}

// ---------------- mask: prod_k cos(fW*rng + fB) ----------------
__global__ void mask_partial_kernel(const float* __restrict__ fW, const float* __restrict__ fB,
                                    float* __restrict__ partial)
{
    int p = blockIdx.x*256 + threadIdx.x;   // 0..15902
    if (p >= 15903) return;
    int w = p % 513;
    float r = (float)(w + 1);
    int k0 = blockIdx.y * 32;
    float prod = 1.0f;
    for (int k = k0; k < k0 + 32; ++k) {
        float a = fW[(size_t)k*15903 + p] * r + fB[(size_t)k*15903 + p];
        prod *= cosf(a);
    }
    partial[blockIdx.y*15903 + p] = prod;
}

__global__ void mask_finalize_apply(const float* __restrict__ partial, const float* __restrict__ x,
                                    float* __restrict__ xm)
{
    int p = blockIdx.x*256 + threadIdx.x;
    if (p >= 15903) return;
    float m = 1.0f;
    #pragma unroll
    for (int c = 0; c < 32; ++c) m *= partial[c*15903 + p];
    for (int n = 0; n < 32; ++n)
        xm[(size_t)n*15903 + p] = x[(size_t)n*15903 + p] * m;
}

// ---------------- weight transforms ----------------
__global__ void wtrans9_kernel(const float* __restrict__ w, unsigned short* __restrict__ o,
                               int Cout, int Cin)
{
    int idx = blockIdx.x*256 + threadIdx.x;
    int cc = Cout*Cin;
    if (idx >= 9*cc) return;
    int tap = idx / cc;
    int r = idx - tap*cc;
    int co = r / Cin, ci = r - co*Cin;
    int kh = tap/3, kw = tap - kh*3;
    o[idx] = f2bf(w[((size_t)(co*Cin + ci)*3 + kh)*3 + kw]);
}
__global__ void wtrans1_kernel(const float* __restrict__ w, unsigned short* __restrict__ o, int total)
{
    int idx = blockIdx.x*256 + threadIdx.x;
    if (idx < total) o[idx] = f2bf(w[idx]);
}

// whh (1024,256) fp32 -> MFMA-fragment-contiguous bf16
__global__ void whh_frag_kernel(const float* __restrict__ whh, unsigned short* __restrict__ out)
{
    int tid = blockIdx.x*256 + threadIdx.x;  // 262144 exact
    int e    = tid & 7;
    int lane = (tid >> 3) & 63;
    int kc   = (tid >> 9) & 7;
    int u0   = (tid >> 12) & 15;
    int g    = tid >> 16;
    int j = (g << 8) + (u0 << 4) + (lane & 15);
    int k = (kc << 5) + ((lane >> 4) << 3) + e;
    out[tid] = f2bf(whh[(size_t)j*256 + k]);
}

// ---------------- conv1: Cin=1 direct, fp32 in -> bf16 NHWC out (rows 1..31 of [33][515][64]) ----------------
__launch_bounds__(256)
__global__ void conv1_kernel(const float* __restrict__ xm, const float* __restrict__ w1,
                             const float* __restrict__ g, const float* __restrict__ b,
                             unsigned short* __restrict__ O)
{
    __shared__ float wl[576];
    __shared__ float sg[64], sb[64];
    int tid = threadIdx.x;
    if (tid < 64) { sg[tid] = g[tid]*RSQ; sb[tid] = b[tid]; }
    for (int i = tid; i < 576; i += 256) wl[i] = w1[i];
    __syncthreads();
    int px = blockIdx.x*256 + tid;
    int n = blockIdx.z;
    if (px >= 15903) return;
    int h = px / 513, w = px - h*513;
    const float* xp = xm + (size_t)n*15903;
    float v[9];
    #pragma unroll
    for (int dh = 0; dh < 3; ++dh)
      #pragma unroll
      for (int dw = 0; dw < 3; ++dw) {
        int hh = h+dh-1, ww = w+dw-1;
        bool ok = ((unsigned)hh < 31u) && ((unsigned)ww < 513u);
        v[dh*3+dw] = ok ? xp[hh*513 + ww] : 0.f;
      }
    unsigned short* op = O + (((size_t)(n*33 + h + 1))*515 + (w + 1))*64;
    #pragma unroll
    for (int c8 = 0; c8 < 8; ++c8) {
        unsigned tmp[8];
        #pragma unroll
        for (int j = 0; j < 8; ++j) {
            int co = c8*8 + j;
            const float* wr = &wl[co*9];
            float a = 0.f;
            #pragma unroll
            for (int t2 = 0; t2 < 9; ++t2) a += wr[t2]*v[t2];
            a = a*sg[co] + sb[co];
            a = (a >= 0.f) ? a : SLOPE*a;
            tmp[j] = f2bf(a);
        }
        uint4 pk;
        pk.x = tmp[0] | (tmp[1]<<16);
        pk.y = tmp[2] | (tmp[3]<<16);
        pk.z = tmp[4] | (tmp[5]<<16);
        pk.w = tmp[6] | (tmp[7]<<16);
        *(uint4*)(op + c8*8) = pk;
    }
}

// ---------------- LDS-staged implicit-GEMM 3x3 conv (+1x1 shortcut) via MFMA ----------------
// Inputs are [33-row][Wp][CIN] bf16, fully zero-padded (rows 0,32 and halo cols zero).
// Block: (w-tile, h) x co64 x n. Stage 3 rows (+shortcut row) into swizzled LDS once,
// reuse across 4 waves x 3 dw taps. POOL=1 fuses bn+lrelu+maxpool(1,4).
template<int CIN, int TPX, int CS, int POOL>
__launch_bounds__(256, 2)
__global__ void conv_lds_kernel(const unsigned short* __restrict__ X,
                                const unsigned short* __restrict__ W9,
                                const unsigned short* __restrict__ Xs,
                                const unsigned short* __restrict__ Ws,
                                unsigned short* __restrict__ O,
                                int Wp, int WT, int WpS,
                                int HO, int HOFF, int WpO, int OOFF, int Cout,
                                const float* __restrict__ g, const float* __restrict__ b)
{
    constexpr int KQ  = CIN/8;
    constexpr int PXT = TPX*16 + 2;
    constexpr int UX  = 3*PXT*KQ;                  // main staged 16B units
    constexpr int KQS = (CS > 0) ? CS/8 : 8;
    constexpr int US  = (CS > 0) ? TPX*16*KQS : 0; // shortcut units
    constexpr int UT  = UX + US;
    constexpr int NU  = (UT + 255)/256;
    constexpr int NKC = CIN/32;
    __shared__ uint4 lds4[UT + 8];

    const int tid = threadIdx.x;
    const int lane = tid & 63;
    const int wave = tid >> 6;
    const int cob  = blockIdx.y*64 + wave*16;
    const int n  = blockIdx.z;
    const int wt = blockIdx.x % WT;
    const int h  = blockIdx.x / WT;
    const int w0 = wt*(TPX*16);
    const int l15 = lane & 15;
    const int gq  = lane >> 4;

    // ---- stage (issue all loads, then swizzled ds_writes) ----
    uint4 tmp[NU];
    #pragma unroll
    for (int i = 0; i < NU; ++i) {
        int u = tid + i*256;
        if (u < UX) {
            int r   = u / (PXT*KQ);
            int rem = u - r*(PXT*KQ);
            int px  = rem / KQ;
            int kq  = rem - px*KQ;
            tmp[i] = *(const uint4*)(X + (((size_t)(n*33 + h + r))*Wp + w0 + px)*CIN + kq*8);
        } else if (CS > 0 && u < UT) {
            int us = u - UX;
            int px = us / KQS;
            int kq = us - px*KQS;
            tmp[i] = *(const uint4*)(Xs + (((size_t)(n*33 + h + 1))*WpS + w0 + 1 + px)*CS + kq*8);
        }
    }
    #pragma unroll
    for (int i = 0; i < NU; ++i) {
        int u = tid + i*256;
        if (u < UT) {
            int px;
            if (u < UX) { int rem = u % (PXT*KQ); px = rem / KQ; }
            else        { px = (u - UX) / KQS; }
            *(uint4*)((char*)lds4 + ((u*16) ^ ((px & 7) << 4))) = tmp[i];
        }
    }
    __syncthreads();

    // ---- compute ----
    f32x4 acc[TPX] = {};
    #pragma unroll
    for (int dh = 0; dh < 3; ++dh) {
        short8 aw[3*NKC];
        #pragma unroll
        for (int dw = 0; dw < 3; ++dw)
            #pragma unroll
            for (int kc = 0; kc < NKC; ++kc)
                aw[dw*NKC + kc] = *(const short8*)(W9 +
                    ((size_t)((dh*3 + dw)*Cout + cob + l15))*CIN + kc*32 + gq*8);
        #pragma unroll
        for (int dw = 0; dw < 3; ++dw) {
            #pragma unroll
            for (int kc = 0; kc < NKC; ++kc) {
                short8 a = aw[dw*NKC + kc];
                #pragma unroll
                for (int t = 0; t < TPX; ++t) {
                    int px = dw + t*16 + l15;
                    int u  = (dh*PXT + px)*KQ + kc*4 + gq;
                    short8 bv = *(const short8*)((const char*)lds4 + ((u*16) ^ ((px & 7) << 4)));
                    acc[t] = __builtin_amdgcn_mfma_f32_16x16x32_bf16(a, bv, acc[t], 0, 0, 0);
                }
            }
        }
    }

    if (CS > 0) {
        #pragma unroll
        for (int kc = 0; kc < KQS/4; ++kc) {
            short8 a = *(const short8*)(Ws + (size_t)(cob + l15)*CS + kc*32 + gq*8);
            #pragma unroll
            for (int t = 0; t < TPX; ++t) {
                int px = t*16 + l15;
                int u  = UX + px*KQS + kc*4 + gq;
                short8 bv = *(const short8*)((const char*)lds4 + ((u*16) ^ ((px & 7) << 4)));
                acc[t] = __builtin_amdgcn_mfma_f32_16x16x32_bf16(a, bv, acc[t], 0, 0, 0);
            }
        }
    }

    // ---- epilogue: bn + lrelu (+maxpool4) -> bf16 ----
    int cb = cob + gq*4;
    float s0 = g[cb+0]*RSQ, s1 = g[cb+1]*RSQ, s2 = g[cb+2]*RSQ, s3 = g[cb+3]*RSQ;
    float o0 = b[cb+0], o1 = b[cb+1], o2 = b[cb+2], o3 = b[cb+3];
    #pragma unroll
    for (int t = 0; t < TPX; ++t) {
        float v0 = acc[t][0]*s0 + o0; v0 = (v0 >= 0.f) ? v0 : SLOPE*v0;
        float v1 = acc[t][1]*s1 + o1; v1 = (v1 >= 0.f) ? v1 : SLOPE*v1;
        float v2 = acc[t][2]*s2 + o2; v2 = (v2 >= 0.f) ? v2 : SLOPE*v2;
        float v3 = acc[t][3]*s3 + o3; v3 = (v3 >= 0.f) ? v3 : SLOPE*v3;
        if (POOL) {
            v0 = fmaxf(v0, __shfl_xor(v0, 1)); v0 = fmaxf(v0, __shfl_xor(v0, 2));
            v1 = fmaxf(v1, __shfl_xor(v1, 1)); v1 = fmaxf(v1, __shfl_xor(v1, 2));
            v2 = fmaxf(v2, __shfl_xor(v2, 1)); v2 = fmaxf(v2, __shfl_xor(v2, 2));
            v3 = fmaxf(v3, __shfl_xor(v3, 1)); v3 = fmaxf(v3, __shfl_xor(v3, 2));
            if ((l15 & 3) == 0) {
                int pw = (w0 + t*16 + l15) >> 2;
                uint2 pk;
                pk.x = (unsigned)f2bf(v0) | ((unsigned)f2bf(v1) << 16);
                pk.y = (unsigned)f2bf(v2) | ((unsigned)f2bf(v3) << 16);
                *(uint2*)(O + (((size_t)(n*HO + h + HOFF))*WpO + pw + OOFF)*Cout + cb) = pk;
            }
        } else {
            int w = w0 + t*16 + l15;
            uint2 pk;
            pk.x = (unsigned)f2bf(v0) | ((unsigned)f2bf(v1) << 16);
            pk.y = (unsigned)f2bf(v2) | ((unsigned)f2bf(v3) << 16);
            *(uint2*)(O + (((size_t)(n*HO + h + HOFF))*WpO + w + OOFF)*Cout + cb) = pk;
        }
    }
}

// ---------------- generic px-tiled conv (kept for W=8 layers) ----------------
__launch_bounds__(256)
__global__ void conv_mfma_kernel(const unsigned short* __restrict__ X,
                                 const unsigned short* __restrict__ W9,
                                 const unsigned short* __restrict__ Xs,
                                 const unsigned short* __restrict__ Ws,
                                 unsigned short* __restrict__ O,
                                 int H, int W, int Cin, int Cs, int Cout,
                                 const float* __restrict__ g, const float* __restrict__ b)
{
    const int HW = H * W;
    const int lane = threadIdx.x & 63;
    const int wave = threadIdx.x >> 6;
    const int co64 = blockIdx.y * 64 + wave * 16;
    const int n = blockIdx.z;
    const int px0 = blockIdx.x * 64;
    const int l15 = lane & 15;
    const int kl = (lane >> 4) * 8;
    const short8 zf = {0,0,0,0,0,0,0,0};

    int hh_[4], ww_[4]; bool pv[4];
    #pragma unroll
    for (int t = 0; t < 4; ++t) {
        int px = px0 + t*16 + l15;
        pv[t] = px < HW;
        int pc = pv[t] ? px : 0;
        hh_[t] = pc / W;
        ww_[t] = pc - hh_[t]*W;
    }

    const unsigned short* Xn = X + (size_t)n * HW * Cin;
    f32x4 acc0 = {0,0,0,0}, acc1 = {0,0,0,0}, acc2 = {0,0,0,0}, acc3 = {0,0,0,0};

    for (int tap = 0; tap < 9; ++tap) {
        int dh = tap/3 - 1, dw = tap - (tap/3)*3 - 1;
        const short8* ap = (const short8*)(W9 + ((size_t)tap*Cout + co64 + l15)*Cin + kl);
        const short8* bp[4]; bool v[4];
        #pragma unroll
        for (int t = 0; t < 4; ++t) {
            int hh = hh_[t] + dh, ww = ww_[t] + dw;
            v[t] = pv[t] && ((unsigned)hh < (unsigned)H) && ((unsigned)ww < (unsigned)W);
            int p2 = v[t] ? (hh*W + ww) : 0;
            bp[t] = (const short8*)(Xn + (size_t)p2*Cin + kl);
        }
        for (int k0 = 0; k0 < Cin; k0 += 32) {
            int ko = k0 >> 3;
            short8 a  = ap[ko];
            short8 b0 = v[0] ? bp[0][ko] : zf;
            short8 b1 = v[1] ? bp[1][ko] : zf;
            short8 b2 = v[2] ? bp[2][ko] : zf;
            short8 b3 = v[3] ? bp[3][ko] : zf;
            acc0 = __builtin_amdgcn_mfma_f32_16x16x32_bf16(a, b0, acc0, 0, 0, 0);
            acc1 = __builtin_amdgcn_mfma_f32_16x16x32_bf16(a, b1, acc1, 0, 0, 0);
            acc2 = __builtin_amdgcn_mfma_f32_16x16x32_bf16(a, b2, acc2, 0, 0, 0);
            acc3 = __builtin_amdgcn_mfma_f32_16x16x32_bf16(a, b3, acc3, 0, 0, 0);
        }
    }

    if (Ws) {
        const unsigned short* X2n = Xs + (size_t)n * HW * Cs;
        const short8* ap = (const short8*)(Ws + ((size_t)(co64 + l15))*Cs + kl);
        const short8* bp[4];
        #pragma unroll
        for (int t = 0; t < 4; ++t) {
            int p2 = pv[t] ? (hh_[t]*W + ww_[t]) : 0;
            bp[t] = (const short8*)(X2n + (size_t)p2*Cs + kl);
        }
        for (int k0 = 0; k0 < Cs; k0 += 32) {
            int ko = k0 >> 3;
            short8 a  = ap[ko];
            short8 b0 = pv[0] ? bp[0][ko] : zf;
            short8 b1 = pv[1] ? bp[1][ko] : zf;
            short8 b2 = pv[2] ? bp[2][ko] : zf;
            short8 b3 = pv[3] ? bp[3][ko] : zf;
            acc0 = __builtin_amdgcn_mfma_f32_16x16x32_bf16(a, b0, acc0, 0, 0, 0);
            acc1 = __builtin_amdgcn_mfma_f32_16x16x32_bf16(a, b1, acc1, 0, 0, 0);
            acc2 = __builtin_amdgcn_mfma_f32_16x16x32_bf16(a, b2, acc2, 0, 0, 0);
            acc3 = __builtin_amdgcn_mfma_f32_16x16x32_bf16(a, b3, acc3, 0, 0, 0);
        }
    }

    int cb = co64 + (lane >> 4)*4;
    float s0 = g[cb+0]*RSQ, s1 = g[cb+1]*RSQ, s2 = g[cb+2]*RSQ, s3 = g[cb+3]*RSQ;
    float o0 = b[cb+0], o1 = b[cb+1], o2 = b[cb+2], o3 = b[cb+3];

#define EPI(ACC, T) do { \
    if (pv[T]) { \
        int px = px0 + (T)*16 + l15; \
        float v0 = ACC[0]*s0 + o0; v0 = (v0 >= 0.f) ? v0 : SLOPE*v0; \
        float v1 = ACC[1]*s1 + o1; v1 = (v1 >= 0.f) ? v1 : SLOPE*v1; \
        float v2 = ACC[2]*s2 + o2; v2 = (v2 >= 0.f) ? v2 : SLOPE*v2; \
        float v3 = ACC[3]*s3 + o3; v3 = (v3 >= 0.f) ? v3 : SLOPE*v3; \
        uint2 pk; \
        pk.x = (unsigned)f2bf(v0) | ((unsigned)f2bf(v1) << 16); \
        pk.y = (unsigned)f2bf(v2) | ((unsigned)f2bf(v3) << 16); \
        *(uint2*)(O + ((size_t)n*HW + px)*Cout + cb) = pk; \
    } \
} while(0)
    EPI(acc0, 0); EPI(acc1, 1); EPI(acc2, 2); EPI(acc3, 3);
#undef EPI
}

// ---------------- maxpool(1,4) VALID on NHWC bf16 (only for final 8->2) ----------------
__global__ void pool_nhwc_kernel(const unsigned short* __restrict__ in,
                                 unsigned short* __restrict__ out,
                                 int Win, int Wout, int WpO, int OOFF, int C, int total8)
{
    int idx = blockIdx.x*256 + threadIdx.x;
    if (idx >= total8) return;
    int c8 = idx % (C >> 3);
    int r = idx / (C >> 3);
    int w = r % Wout;
    int nh = r / Wout;
    const unsigned short* ip = in + (((size_t)nh*Win) + (size_t)w*4)*C + c8*8;
    float m0=-1e30f,m1=-1e30f,m2=-1e30f,m3=-1e30f,m4=-1e30f,m5=-1e30f,m6=-1e30f,m7=-1e30f;
    #pragma unroll
    for (int i = 0; i < 4; ++i) {
        uint4 u = *(const uint4*)(ip + (size_t)i*C);
        m0 = fmaxf(m0, bf2f((unsigned short)(u.x & 0xffff)));
        m1 = fmaxf(m1, bf2f((unsigned short)(u.x >> 16)));
        m2 = fmaxf(m2, bf2f((unsigned short)(u.y & 0xffff)));
        m3 = fmaxf(m3, bf2f((unsigned short)(u.y >> 16)));
        m4 = fmaxf(m4, bf2f((unsigned short)(u.z & 0xffff)));
        m5 = fmaxf(m5, bf2f((unsigned short)(u.z >> 16)));
        m6 = fmaxf(m6, bf2f((unsigned short)(u.w & 0xffff)));
        m7 = fmaxf(m7, bf2f((unsigned short)(u.w >> 16)));
    }
    uint4 ov;
    ov.x = (unsigned)f2bf(m0) | ((unsigned)f2bf(m1) << 16);
    ov.y = (unsigned)f2bf(m2) | ((unsigned)f2bf(m3) << 16);
    ov.z = (unsigned)f2bf(m4) | ((unsigned)f2bf(m5) << 16);
    ov.w = (unsigned)f2bf(m6) | ((unsigned)f2bf(m7) << 16);
    *(uint4*)(out + (((size_t)nh*WpO) + w + OOFF)*C + c8*8) = ov;
}

// ---------------- feats: [n][31][2][256] bf16 NHWC -> [n][31][512] fp32 ----------------
__global__ void feats_kernel(const unsigned short* __restrict__ p4, float* __restrict__ fe)
{
    int idx = blockIdx.x*256 + threadIdx.x;   // 507904
    int cw = idx & 511;
    int nh = idx >> 9;
    int c = cw >> 1, w = cw & 1;
    fe[idx] = bf2f(p4[((size_t)nh*2 + w)*256 + c]);
}

// ---------------- tiled SGEMM: C[M,N] = A[M,K] @ B[N,K]^T + bias(+bias2) ----------------
#define GM 32
#define GN 64
#define GK 32
template<int XPOSE>
__launch_bounds__(256)
__global__ void gemm_bias_kernel(const float* __restrict__ A, const float* __restrict__ B,
                                 const float* __restrict__ bias, const float* __restrict__ bias2,
                                 float* __restrict__ C, int M, int N, int K)
{
    __shared__ float As[GM][GK+1];
    __shared__ float Bs[GN][GK+1];
    int m0 = blockIdx.x*GM, n0 = blockIdx.y*GN;
    int tid = threadIdx.x;
    int mi = tid >> 4;
    int ni = (tid & 15) * 4;
    float acc[2][4] = {};

    for (int k0 = 0; k0 < K; k0 += GK) {
        for (int i = tid; i < GM*GK; i += 256) {
            int r = i >> 5, c = i & 31;
            int m = m0 + r;
            As[r][c] = (m < M) ? A[(size_t)m*K + k0 + c] : 0.f;
        }
        for (int i = tid; i < GN*GK; i += 256) {
            int r = i >> 5, c = i & 31;
            int n = n0 + r;
            Bs[r][c] = (n < N) ? B[(size_t)n*K + k0 + c] : 0.f;
        }
        __syncthreads();
        #pragma unroll
        for (int kk = 0; kk < GK; ++kk) {
            float a0 = As[mi][kk], a1 = As[mi+16][kk];
            float b0 = Bs[ni][kk], b1 = Bs[ni+1][kk], b2 = Bs[ni+2][kk], b3 = Bs[ni+3][kk];
            acc[0][0] += a0*b0; acc[0][1] += a0*b1; acc[0][2] += a0*b2; acc[0][3] += a0*b3;
            acc[1][0] += a1*b0; acc[1][1] += a1*b1; acc[1][2] += a1*b2; acc[1][3] += a1*b3;
        }
        __syncthreads();
    }
    #pragma unroll
    for (int r = 0; r < 2; ++r) {
        int m = m0 + mi + r*16;
        if (m >= M) continue;
        #pragma unroll
        for (int q = 0; q < 4; ++q) {
            int n = n0 + ni + q;
            if (n >= N) continue;
            float v = acc[r][q];
            if (bias)  v += bias[n];
            if (bias2) v += bias2[n];
            if (XPOSE) C[((size_t)(m % 31)*32 + (m / 31))*N + n] = v;
            else       C[(size_t)m*N + n] = v;
        }
    }
}

// ---------------- LSTM scan via MFMA: 4 blocks = (dir x batch-half), 1024 thr ----------------
__launch_bounds__(1024, 4)
__global__ void lstm_scan_mfma(const float* __restrict__ xpT,
                               const unsigned short* __restrict__ wf,
                               float* __restrict__ hcat)
{
    const int d  = blockIdx.x >> 1;
    const int bh = blockIdx.x & 1;
    const int tid = threadIdx.x;
    const int u0 = tid >> 6;
    const int lane = tid & 63;
    const int l15 = lane & 15;
    const int q = lane >> 4;

    __shared__ unsigned short hbuf[2][4096];
    ((int4*)hbuf)[tid] = make_int4(0,0,0,0);
    __syncthreads();

    const unsigned short* wfd = wf + (size_t)d*262144;
    const float* xpd = xpT + (size_t)d*992*1024 + (size_t)bh*16*1024;
    const unsigned short* wp = wfd + u0*4096 + lane*8;

    float c0=0.f, c1=0.f, c2=0.f, c3=0.f;
    const int ubase = u0*16 + q*4;
    const int rb = l15*512 + q*16;
    const int xr = (l15&7)<<4;

#define WLD(kc,g) (*(const short8*)(wp + (kc)*512 + (g)*65536))
#define HRD(kc)   (*(const short8*)(hb + ((rb + (kc)*64) ^ xr)))
#define MF(w_,h_,a_) a_ = __builtin_amdgcn_mfma_f32_16x16x32_bf16(w_, h_, a_, 0, 0, 0)

    for (int s = 0; s < 31; ++s) {
        const int t = d ? (30 - s) : s;
        const int cur = s & 1, nxt = cur ^ 1;
        const float* xb = xpd + (size_t)t*32768 + (size_t)l15*1024;
        float4 xi = *(const float4*)(xb + ubase);
        float4 xf = *(const float4*)(xb + 256 + ubase);
        float4 xg = *(const float4*)(xb + 512 + ubase);
        float4 xo = *(const float4*)(xb + 768 + ubase);

        const char* hb = (const char*)hbuf[cur];
        f32x4 a0={0,0,0,0}, a1={0,0,0,0}, a2={0,0,0,0}, a3={0,0,0,0};

        short8 wA0=WLD(0,0), wA1=WLD(0,1), wA2=WLD(0,2), wA3=WLD(0,3);
        short8 wB0=WLD(1,0), wB1=WLD(1,1), wB2=WLD(1,2), wB3=WLD(1,3);
        short8 wC0=WLD(2,0), wC1=WLD(2,1), wC2=WLD(2,2), wC3=WLD(2,3);
        short8 wD0=WLD(3,0), wD1=WLD(3,1), wD2=WLD(3,2), wD3=WLD(3,3);

        { short8 h=HRD(0); MF(wA0,h,a0); MF(wA1,h,a1); MF(wA2,h,a2); MF(wA3,h,a3); }
        wA0=WLD(4,0); wA1=WLD(4,1); wA2=WLD(4,2); wA3=WLD(4,3);
        { short8 h=HRD(1); MF(wB0,h,a0); MF(wB1,h,a1); MF(wB2,h,a2); MF(wB3,h,a3); }
        wB0=WLD(5,0); wB1=WLD(5,1); wB2=WLD(5,2); wB3=WLD(5,3);
        { short8 h=HRD(2); MF(wC0,h,a0); MF(wC1,h,a1); MF(wC2,h,a2); MF(wC3,h,a3); }
        wC0=WLD(6,0); wC1=WLD(6,1); wC2=WLD(6,2); wC3=WLD(6,3);
        { short8 h=HRD(3); MF(wD0,h,a0); MF(wD1,h,a1); MF(wD2,h,a2); MF(wD3,h,a3); }
        wD0=WLD(7,0); wD1=WLD(7,1); wD2=WLD(7,2); wD3=WLD(7,3);
        { short8 h=HRD(4); MF(wA0,h,a0); MF(wA1,h,a1); MF(wA2,h,a2); MF(wA3,h,a3); }
        { short8 h=HRD(5); MF(wB0,h,a0); MF(wB1,h,a1); MF(wB2,h,a2); MF(wB3,h,a3); }
        { short8 h=HRD(6); MF(wC0,h,a0); MF(wC1,h,a1); MF(wC2,h,a2); MF(wC3,h,a3); }
        { short8 h=HRD(7); MF(wD0,h,a0); MF(wD1,h,a1); MF(wD2,h,a2); MF(wD3,h,a3); }

        float hv0, hv1, hv2, hv3;
        { float gi=a0[0]+xi.x, gf=a1[0]+xf.x, gg=a2[0]+xg.x, go=a3[0]+xo.x;
          float cn = sigmoidf_(gf)*c0 + sigmoidf_(gi)*tanhf(gg); c0 = cn; hv0 = sigmoidf_(go)*tanhf(cn); }
        { float gi=a0[1]+xi.y, gf=a1[1]+xf.y, gg=a2[1]+xg.y, go=a3[1]+xo.y;
          float cn = sigmoidf_(gf)*c1 + sigmoidf_(gi)*tanhf(gg); c1 = cn; hv1 = sigmoidf_(go)*tanhf(cn); }
        { float gi=a0[2]+xi.z, gf=a1[2]+xf.z, gg=a2[2]+xg.z, go=a3[2]+xo.z;
          float cn = sigmoidf_(gf)*c2 + sigmoidf_(gi)*tanhf(gg); c2 = cn; hv2 = sigmoidf_(go)*tanhf(cn); }
        { float gi=a0[3]+xi.w, gf=a1[3]+xf.w, gg=a2[3]+xg.w, go=a3[3]+xo.w;
          float cn = sigmoidf_(gf)*c3 + sigmoidf_(gi)*tanhf(gg); c3 = cn; hv3 = sigmoidf_(go)*tanhf(cn); }

        short4 hp;
        hp.x = (short)f2bf(hv0); hp.y = (short)f2bf(hv1);
        hp.z = (short)f2bf(hv2); hp.w = (short)f2bf(hv3);
        *(short4*)((char*)hbuf[nxt] + ((l15*512 + ubase*2) ^ xr)) = hp;
        int bg = bh*16 + l15;
        *(float4*)(&hcat[((size_t)bg*31 + t)*512 + (size_t)d*256 + ubase]) =
            make_float4(hv0, hv1, hv2, hv3);

        __syncthreads();
    }
#undef WLD
#undef HRD
#undef MF
}

extern "C" void kernel_launch(void* const* d_in, const int* in_sizes, int n_in,
                              void* d_out, int out_size, void* d_ws, size_t ws_size,
                              hipStream_t stream)
{
    const float* x    = (const float*)d_in[0];
    const float* fW   = (const float*)d_in[1];
    const float* fB   = (const float*)d_in[2];
    const float* cbw1 = (const float*)d_in[3];
    const float* cbg  = (const float*)d_in[4];
    const float* cbb  = (const float*)d_in[5];
    const float* cbw2 = (const float*)d_in[6];
    const float* r1pg = (const float*)d_in[7];
    const float* r1pb = (const float*)d_in[8];
    const float* r1wA = (const float*)d_in[9];
    const float* r1g  = (const float*)d_in[10];
    const float* r1b  = (const float*)d_in[11];
    const float* r1wB = (const float*)d_in[12];
    const float* r1s  = (const float*)d_in[13];
    const float* r2pg = (const float*)d_in[14];
    const float* r2pb = (const float*)d_in[15];
    const float* r2wA = (const float*)d_in[16];
    const float* r2g  = (const float*)d_in[17];
    const float* r2b  = (const float*)d_in[18];
    const float* r2wB = (const float*)d_in[19];
    const float* r2s  = (const float*)d_in[20];
    const float* r3pg = (const float*)d_in[21];
    const float* r3pb = (const float*)d_in[22];
    const float* r3wA = (const float*)d_in[23];
    const float* r3g  = (const float*)d_in[24];
    const float* r3b  = (const float*)d_in[25];
    const float* r3wB = (const float*)d_in[26];
    const float* r3s  = (const float*)d_in[27];
    const float* pbg  = (const float*)d_in[28];
    const float* pbb  = (const float*)d_in[29];
    const float* wih_f = (const float*)d_in[30];
    const float* whh_f = (const float*)d_in[31];
    const float* bih_f = (const float*)d_in[32];
    const float* bhh_f = (const float*)d_in[33];
    const float* wih_b = (const float*)d_in[34];
    const float* whh_b = (const float*)d_in[35];
    const float* bih_b = (const float*)d_in[36];
    const float* bhh_b = (const float*)d_in[37];
    const float* clsw  = (const float*)d_in[38];
    const float* clsb  = (const float*)d_in[39];
    float* out = (float*)d_out;
    float* ws  = (float*)d_ws;

    // ---- workspace sizing ----
    // fixed floats: WTR 962560 + P 508896 + XM 508896 + XP4 253952 + FE 507904
    //             + WF 262144 + XPT 2031616 + HC 507904 = 5543872
    const size_t FIXEDF = 5543872;
    // per-img shorts (h-padded 33-row buffers):
    //   A1 33*515*64=1,087,680  C1p 33*130*64=274,560  A2 33*130*128=549,120
    //   C2p 33*34*128=143,616   A3 33*34*192=215,424   XP3 47,616  A4 63,488  B4 63,488
    const size_t PADDED_SHORTS = 2270400;   // A1..A3, memset region
    const size_t PCS = 2444992;             // all per-img shorts
    const size_t PCF = (PCS + 1)/2;
    int NC = 0;
    const int cands[6] = {32,16,8,4,2,1};
    for (int i = 0; i < 6; ++i) {
        if ((FIXEDF + (size_t)cands[i]*PCF + 64)*sizeof(float) <= ws_size) { NC = cands[i]; break; }
    }
    if (!NC) return;

    float* p = ws;
    unsigned short* WTR = (unsigned short*)p; p += 962560;
    float* P   = p; p += 508896;
    float* XM  = p; p += 508896;
    unsigned short* XP4 = (unsigned short*)p; p += 253952;
    float* FE  = p; p += 507904;
    unsigned short* WF = (unsigned short*)p; p += 262144;
    float* XPT = p; p += 2031616;
    float* HC  = p; p += 507904;
    unsigned short* q = (unsigned short*)p;
    unsigned short* A1  = q; q += (size_t)NC*1087680;
    unsigned short* C1p = q; q += (size_t)NC*274560;
    unsigned short* A2  = q; q += (size_t)NC*549120;
    unsigned short* C2p = q; q += (size_t)NC*143616;
    unsigned short* A3  = q; q += (size_t)NC*215424;
    unsigned short* XP3 = q; q += (size_t)NC*47616;
    unsigned short* A4  = q; q += (size_t)NC*63488;
    unsigned short* B4  = q; q += (size_t)NC*63488;

    unsigned short* w2T  = WTR + 0;
    unsigned short* r1AT = WTR + 36864;
    unsigned short* r1BT = WTR + 110592;
    unsigned short* r1ST = WTR + 258048;
    unsigned short* r2AT = WTR + 266240;
    unsigned short* r2BT = WTR + 487424;
    unsigned short* r2ST = WTR + 819200;
    unsigned short* r3AT = WTR + 843776;
    unsigned short* r3BT = WTR + 1286144;
    unsigned short* r3ST = WTR + 1875968;

    auto cdiv = [](int a, int b){ return (a + b - 1) / b; };

    // ---- weight transforms ----
    wtrans9_kernel<<<cdiv(9*64*64,256),   256, 0, stream>>>(cbw2, w2T, 64, 64);
    wtrans9_kernel<<<cdiv(9*128*64,256),  256, 0, stream>>>(r1wA, r1AT, 128, 64);
    wtrans9_kernel<<<cdiv(9*128*128,256), 256, 0, stream>>>(r1wB, r1BT, 128, 128);
    wtrans1_kernel<<<cdiv(128*64,256),    256, 0, stream>>>(r1s, r1ST, 128*64);
    wtrans9_kernel<<<cdiv(9*192*128,256), 256, 0, stream>>>(r2wA, r2AT, 192, 128);
    wtrans9_kernel<<<cdiv(9*192*192,256), 256, 0, stream>>>(r2wB, r2BT, 192, 192);
    wtrans1_kernel<<<cdiv(192*128,256),   256, 0, stream>>>(r2s, r2ST, 192*128);
    wtrans9_kernel<<<cdiv(9*256*192,256), 256, 0, stream>>>(r3wA, r3AT, 256, 192);
    wtrans9_kernel<<<cdiv(9*256*256,256), 256, 0, stream>>>(r3wB, r3BT, 256, 256);
    wtrans1_kernel<<<cdiv(256*192,256),   256, 0, stream>>>(r3s, r3ST, 256*192);
    whh_frag_kernel<<<1024, 256, 0, stream>>>(whh_f, WF);
    whh_frag_kernel<<<1024, 256, 0, stream>>>(whh_b, WF + 262144);

    // ---- frontend mask ----
    mask_partial_kernel<<<dim3(63, 32), 256, 0, stream>>>(fW, fB, P);
    mask_finalize_apply<<<63, 256, 0, stream>>>(P, x, XM);

    // ---- zero padded staging region (h/w halos stay zero) ----
    hipMemsetAsync(A1, 0, (size_t)NC*PADDED_SHORTS*sizeof(unsigned short), stream);

    // ---- conv stack, chunked over batch ----
    for (int c0 = 0; c0 < 32; c0 += NC) {
        const float* xmc = XM + (size_t)c0*15903;
        // conv1: 1->64, out A1 [33][515][64] rows 1..31
        conv1_kernel<<<dim3(63, 1, NC), 256, 0, stream>>>(xmc, cbw1, cbg, cbb, A1);
        // conv2 + bn(r1pg,r1pb)+lrelu+pool4: 64ch, 513->128, out C1p [33][130][64]
        conv_lds_kernel<64,8,0,1><<<dim3(4*31, 1, NC), 256, 0, stream>>>(
            A1, w2T, nullptr, nullptr, C1p, 515, 4, 0, 33, 1, 130, 1, 64, r1pg, r1pb);
        // r1A: 64->128, out A2 [33][130][128]
        conv_lds_kernel<64,8,0,0><<<dim3(31, 2, NC), 256, 0, stream>>>(
            C1p, r1AT, nullptr, nullptr, A2, 130, 1, 0, 33, 1, 130, 1, 128, r1g, r1b);
        // r1B + shortcut + bn(r2pg,r2pb)+lrelu+pool4: 128->32, out C2p [33][34][128]
        conv_lds_kernel<128,8,64,1><<<dim3(31, 2, NC), 256, 0, stream>>>(
            A2, r1BT, C1p, r1ST, C2p, 130, 1, 130, 33, 1, 34, 1, 128, r2pg, r2pb);
        // r2A: 128->192, out A3 [33][34][192]
        conv_lds_kernel<128,2,0,0><<<dim3(31, 3, NC), 256, 0, stream>>>(
            C2p, r2AT, nullptr, nullptr, A3, 34, 1, 0, 33, 1, 34, 1, 192, r2g, r2b);
        // r2B + shortcut + bn(r3pg,r3pb)+lrelu+pool4: 32->8, out XP3 [31][8][192] (unpadded)
        conv_lds_kernel<192,2,128,1><<<dim3(31, 3, NC), 256, 0, stream>>>(
            A3, r2BT, C2p, r2ST, XP3, 34, 1, 34, 31, 0, 8, 0, 192, r3pg, r3pb);
        // r3 (W=8): generic kernels
        conv_mfma_kernel<<<dim3(4, 4, NC), 256, 0, stream>>>(
            XP3, r3AT, nullptr, nullptr, A4, 31, 8, 192, 0, 256, r3g, r3b);
        conv_mfma_kernel<<<dim3(4, 4, NC), 256, 0, stream>>>(
            A4, r3BT, XP3, r3ST, B4, 31, 8, 256, 192, 256, pbg, pbb);
        // final pool 8->2 -> XP4 slice
        pool_nhwc_kernel<<<cdiv(NC*31*2*32,256), 256, 0, stream>>>(
            B4, XP4 + (size_t)c0*15872, 8, 2, 2, 0, 256, NC*31*2*32);
    }

    // feats (32,31,512) fp32
    feats_kernel<<<1984, 256, 0, stream>>>(XP4, FE);

    // LSTM input projections -> xpT [d][t][b][j]
    gemm_bias_kernel<1><<<dim3(31, 16), 256, 0, stream>>>(FE, wih_f, bih_f, bhh_f, XPT,           992, 1024, 512);
    gemm_bias_kernel<1><<<dim3(31, 16), 256, 0, stream>>>(FE, wih_b, bih_b, bhh_b, XPT + 1015808, 992, 1024, 512);

    // fused bidirectional scan (4 blocks: dir x batch-half)
    lstm_scan_mfma<<<4, 1024, 0, stream>>>(XPT, WF, HC);

    // classifier -> d_out (32,31,722)
    gemm_bias_kernel<0><<<dim3(31, 12), 256, 0, stream>>>(HC, clsw, clsb, nullptr, out, 992, 722, 512);
}

// Round 11
// 1374.054 us; speedup vs baseline: 1.5036x; 1.0469x over previous
//
#include <hip/hip_runtime.h>
#include <hip/hip_bf16.h>
#include <math.h>

#define RSQ 0.99999500003749969f   // 1/sqrt(1+1e-5)
#define SLOPE 0.01f

typedef __attribute__((ext_vector_type(8))) short short8;
typedef __attribute__((ext_vector_type(4))) float f32x4;

__device__ __forceinline__ float sigmoidf_(float x){ return 1.0f/(1.0f+expf(-x)); }

__device__ __forceinline__ unsigned short f2bf(float f){
    unsigned u = __float_as_uint(f);
    u += 0x7fff + ((u >> 16) & 1);      // RNE
    return (unsigned short)(u >> 16);
}
__device__ __forceinline__ float bf2f(unsigned short s){
    return __uint_as_float(((unsigned)s) << 16);
}

// async global->LDS, 16B per lane; LDS dest is wave-uniform base + lane*16
__device__ __forceinline__ void stage16(const unsigned short* g, unsigned short* l) {
    __builtin_amdgcn_global_load_lds(
        (const __attribute__((address_space(1))) unsigned int*)g,
        (__attribute__((address_space(3))) unsigned int*)l, 16, 0, 0);
}

// ---------------- mask: prod_k cos(fW*rng + fB) ----------------
__global__ void mask_partial_kernel(const float* __restrict__ fW, const float* __restrict__ fB,
                                    float* __restrict__ partial)
{
    int p = blockIdx.x*256 + threadIdx.x;   // 0..15902
    if (p >= 15903) return;
    int w = p % 513;
    float r = (float)(w + 1);
    int k0 = blockIdx.y * 32;
    float prod = 1.0f;
    for (int k = k0; k < k0 + 32; ++k) {
        float a = fW[(size_t)k*15903 + p] * r + fB[(size_t)k*15903 + p];
        prod *= cosf(a);
    }
    partial[blockIdx.y*15903 + p] = prod;
}

__global__ void mask_finalize_apply(const float* __restrict__ partial, const float* __restrict__ x,
                                    float* __restrict__ xm)
{
    int p = blockIdx.x*256 + threadIdx.x;
    if (p >= 15903) return;
    float m = 1.0f;
    #pragma unroll
    for (int c = 0; c < 32; ++c) m *= partial[c*15903 + p];
    for (int n = 0; n < 32; ++n)
        xm[(size_t)n*15903 + p] = x[(size_t)n*15903 + p] * m;
}

// ---------------- weight transforms ----------------
__global__ void wtrans9_kernel(const float* __restrict__ w, unsigned short* __restrict__ o,
                               int Cout, int Cin)
{
    int idx = blockIdx.x*256 + threadIdx.x;
    int cc = Cout*Cin;
    if (idx >= 9*cc) return;
    int tap = idx / cc;
    int r = idx - tap*cc;
    int co = r / Cin, ci = r - co*Cin;
    int kh = tap/3, kw = tap - kh*3;
    o[idx] = f2bf(w[((size_t)(co*Cin + ci)*3 + kh)*3 + kw]);
}
__global__ void wtrans1_kernel(const float* __restrict__ w, unsigned short* __restrict__ o, int total)
{
    int idx = blockIdx.x*256 + threadIdx.x;
    if (idx < total) o[idx] = f2bf(w[idx]);
}

// whh (1024,256) fp32 -> MFMA-fragment-contiguous bf16
__global__ void whh_frag_kernel(const float* __restrict__ whh, unsigned short* __restrict__ out)
{
    int tid = blockIdx.x*256 + threadIdx.x;  // 262144 exact
    int e    = tid & 7;
    int lane = (tid >> 3) & 63;
    int kc   = (tid >> 9) & 7;
    int u0   = (tid >> 12) & 15;
    int g    = tid >> 16;
    int j = (g << 8) + (u0 << 4) + (lane & 15);
    int k = (kc << 5) + ((lane >> 4) << 3) + e;
    out[tid] = f2bf(whh[(size_t)j*256 + k]);
}

// ---------------- conv1: Cin=1 direct, fp32 in -> bf16 NHWC out (rows 1..31 of [33][515][64]) ----------------
__launch_bounds__(256)
__global__ void conv1_kernel(const float* __restrict__ xm, const float* __restrict__ w1,
                             const float* __restrict__ g, const float* __restrict__ b,
                             unsigned short* __restrict__ O)
{
    __shared__ float wl[576];
    __shared__ float sg[64], sb[64];
    int tid = threadIdx.x;
    if (tid < 64) { sg[tid] = g[tid]*RSQ; sb[tid] = b[tid]; }
    for (int i = tid; i < 576; i += 256) wl[i] = w1[i];
    __syncthreads();
    int px = blockIdx.x*256 + tid;
    int n = blockIdx.z;
    if (px >= 15903) return;
    int h = px / 513, w = px - h*513;
    const float* xp = xm + (size_t)n*15903;
    float v[9];
    #pragma unroll
    for (int dh = 0; dh < 3; ++dh)
      #pragma unroll
      for (int dw = 0; dw < 3; ++dw) {
        int hh = h+dh-1, ww = w+dw-1;
        bool ok = ((unsigned)hh < 31u) && ((unsigned)ww < 513u);
        v[dh*3+dw] = ok ? xp[hh*513 + ww] : 0.f;
      }
    unsigned short* op = O + (((size_t)(n*33 + h + 1))*515 + (w + 1))*64;
    #pragma unroll
    for (int c8 = 0; c8 < 8; ++c8) {
        unsigned tmp[8];
        #pragma unroll
        for (int j = 0; j < 8; ++j) {
            int co = c8*8 + j;
            const float* wr = &wl[co*9];
            float a = 0.f;
            #pragma unroll
            for (int t2 = 0; t2 < 9; ++t2) a += wr[t2]*v[t2];
            a = a*sg[co] + sb[co];
            a = (a >= 0.f) ? a : SLOPE*a;
            tmp[j] = f2bf(a);
        }
        uint4 pk;
        pk.x = tmp[0] | (tmp[1]<<16);
        pk.y = tmp[2] | (tmp[3]<<16);
        pk.z = tmp[4] | (tmp[5]<<16);
        pk.w = tmp[6] | (tmp[7]<<16);
        *(uint4*)(op + c8*8) = pk;
    }
}

// ---------------- LDS-staged implicit-GEMM 3x3 conv (+1x1 shortcut) via MFMA ----------------
template<int CIN, int TPX, int CS, int POOL>
__launch_bounds__(256, 2)
__global__ void conv_lds_kernel(const unsigned short* __restrict__ X,
                                const unsigned short* __restrict__ W9,
                                const unsigned short* __restrict__ Xs,
                                const unsigned short* __restrict__ Ws,
                                unsigned short* __restrict__ O,
                                int Wp, int WT, int WpS,
                                int HO, int HOFF, int WpO, int OOFF, int Cout,
                                const float* __restrict__ g, const float* __restrict__ b)
{
    constexpr int KQ  = CIN/8;
    constexpr int PXT = TPX*16 + 2;
    constexpr int UX  = 3*PXT*KQ;
    constexpr int KQS = (CS > 0) ? CS/8 : 8;
    constexpr int US  = (CS > 0) ? TPX*16*KQS : 0;
    constexpr int UT  = UX + US;
    constexpr int NU  = (UT + 255)/256;
    constexpr int NKC = CIN/32;
    __shared__ uint4 lds4[UT + 8];

    const int tid = threadIdx.x;
    const int lane = tid & 63;
    const int wave = tid >> 6;
    const int cob  = blockIdx.y*64 + wave*16;
    const int n  = blockIdx.z;
    const int wt = blockIdx.x % WT;
    const int h  = blockIdx.x / WT;
    const int w0 = wt*(TPX*16);
    const int l15 = lane & 15;
    const int gq  = lane >> 4;

    uint4 tmp[NU];
    #pragma unroll
    for (int i = 0; i < NU; ++i) {
        int u = tid + i*256;
        if (u < UX) {
            int r   = u / (PXT*KQ);
            int rem = u - r*(PXT*KQ);
            int px  = rem / KQ;
            int kq  = rem - px*KQ;
            tmp[i] = *(const uint4*)(X + (((size_t)(n*33 + h + r))*Wp + w0 + px)*CIN + kq*8);
        } else if (CS > 0 && u < UT) {
            int us = u - UX;
            int px = us / KQS;
            int kq = us - px*KQS;
            tmp[i] = *(const uint4*)(Xs + (((size_t)(n*33 + h + 1))*WpS + w0 + 1 + px)*CS + kq*8);
        }
    }
    #pragma unroll
    for (int i = 0; i < NU; ++i) {
        int u = tid + i*256;
        if (u < UT) {
            int px;
            if (u < UX) { int rem = u % (PXT*KQ); px = rem / KQ; }
            else        { px = (u - UX) / KQS; }
            *(uint4*)((char*)lds4 + ((u*16) ^ ((px & 7) << 4))) = tmp[i];
        }
    }
    __syncthreads();

    f32x4 acc[TPX] = {};
    #pragma unroll
    for (int dh = 0; dh < 3; ++dh) {
        short8 aw[3*NKC];
        #pragma unroll
        for (int dw = 0; dw < 3; ++dw)
            #pragma unroll
            for (int kc = 0; kc < NKC; ++kc)
                aw[dw*NKC + kc] = *(const short8*)(W9 +
                    ((size_t)((dh*3 + dw)*Cout + cob + l15))*CIN + kc*32 + gq*8);
        #pragma unroll
        for (int dw = 0; dw < 3; ++dw) {
            #pragma unroll
            for (int kc = 0; kc < NKC; ++kc) {
                short8 a = aw[dw*NKC + kc];
                #pragma unroll
                for (int t = 0; t < TPX; ++t) {
                    int px = dw + t*16 + l15;
                    int u  = (dh*PXT + px)*KQ + kc*4 + gq;
                    short8 bv = *(const short8*)((const char*)lds4 + ((u*16) ^ ((px & 7) << 4)));
                    acc[t] = __builtin_amdgcn_mfma_f32_16x16x32_bf16(a, bv, acc[t], 0, 0, 0);
                }
            }
        }
    }

    if (CS > 0) {
        #pragma unroll
        for (int kc = 0; kc < KQS/4; ++kc) {
            short8 a = *(const short8*)(Ws + (size_t)(cob + l15)*CS + kc*32 + gq*8);
            #pragma unroll
            for (int t = 0; t < TPX; ++t) {
                int px = t*16 + l15;
                int u  = UX + px*KQS + kc*4 + gq;
                short8 bv = *(const short8*)((const char*)lds4 + ((u*16) ^ ((px & 7) << 4)));
                acc[t] = __builtin_amdgcn_mfma_f32_16x16x32_bf16(a, bv, acc[t], 0, 0, 0);
            }
        }
    }

    int cb = cob + gq*4;
    float s0 = g[cb+0]*RSQ, s1 = g[cb+1]*RSQ, s2 = g[cb+2]*RSQ, s3 = g[cb+3]*RSQ;
    float o0 = b[cb+0], o1 = b[cb+1], o2 = b[cb+2], o3 = b[cb+3];
    #pragma unroll
    for (int t = 0; t < TPX; ++t) {
        float v0 = acc[t][0]*s0 + o0; v0 = (v0 >= 0.f) ? v0 : SLOPE*v0;
        float v1 = acc[t][1]*s1 + o1; v1 = (v1 >= 0.f) ? v1 : SLOPE*v1;
        float v2 = acc[t][2]*s2 + o2; v2 = (v2 >= 0.f) ? v2 : SLOPE*v2;
        float v3 = acc[t][3]*s3 + o3; v3 = (v3 >= 0.f) ? v3 : SLOPE*v3;
        if (POOL) {
            v0 = fmaxf(v0, __shfl_xor(v0, 1)); v0 = fmaxf(v0, __shfl_xor(v0, 2));
            v1 = fmaxf(v1, __shfl_xor(v1, 1)); v1 = fmaxf(v1, __shfl_xor(v1, 2));
            v2 = fmaxf(v2, __shfl_xor(v2, 1)); v2 = fmaxf(v2, __shfl_xor(v2, 2));
            v3 = fmaxf(v3, __shfl_xor(v3, 1)); v3 = fmaxf(v3, __shfl_xor(v3, 2));
            if ((l15 & 3) == 0) {
                int pw = (w0 + t*16 + l15) >> 2;
                uint2 pk;
                pk.x = (unsigned)f2bf(v0) | ((unsigned)f2bf(v1) << 16);
                pk.y = (unsigned)f2bf(v2) | ((unsigned)f2bf(v3) << 16);
                *(uint2*)(O + (((size_t)(n*HO + h + HOFF))*WpO + pw + OOFF)*Cout + cb) = pk;
            }
        } else {
            int w = w0 + t*16 + l15;
            uint2 pk;
            pk.x = (unsigned)f2bf(v0) | ((unsigned)f2bf(v1) << 16);
            pk.y = (unsigned)f2bf(v2) | ((unsigned)f2bf(v3) << 16);
            *(uint2*)(O + (((size_t)(n*HO + h + HOFF))*WpO + w + OOFF)*Cout + cb) = pk;
        }
    }
}

// ---------------- generic px-tiled conv (kept for W=8 layers) ----------------
__launch_bounds__(256)
__global__ void conv_mfma_kernel(const unsigned short* __restrict__ X,
                                 const unsigned short* __restrict__ W9,
                                 const unsigned short* __restrict__ Xs,
                                 const unsigned short* __restrict__ Ws,
                                 unsigned short* __restrict__ O,
                                 int H, int W, int Cin, int Cs, int Cout,
                                 const float* __restrict__ g, const float* __restrict__ b)
{
    const int HW = H * W;
    const int lane = threadIdx.x & 63;
    const int wave = threadIdx.x >> 6;
    const int co64 = blockIdx.y * 64 + wave * 16;
    const int n = blockIdx.z;
    const int px0 = blockIdx.x * 64;
    const int l15 = lane & 15;
    const int kl = (lane >> 4) * 8;
    const short8 zf = {0,0,0,0,0,0,0,0};

    int hh_[4], ww_[4]; bool pv[4];
    #pragma unroll
    for (int t = 0; t < 4; ++t) {
        int px = px0 + t*16 + l15;
        pv[t] = px < HW;
        int pc = pv[t] ? px : 0;
        hh_[t] = pc / W;
        ww_[t] = pc - hh_[t]*W;
    }

    const unsigned short* Xn = X + (size_t)n * HW * Cin;
    f32x4 acc0 = {0,0,0,0}, acc1 = {0,0,0,0}, acc2 = {0,0,0,0}, acc3 = {0,0,0,0};

    for (int tap = 0; tap < 9; ++tap) {
        int dh = tap/3 - 1, dw = tap - (tap/3)*3 - 1;
        const short8* ap = (const short8*)(W9 + ((size_t)tap*Cout + co64 + l15)*Cin + kl);
        const short8* bp[4]; bool v[4];
        #pragma unroll
        for (int t = 0; t < 4; ++t) {
            int hh = hh_[t] + dh, ww = ww_[t] + dw;
            v[t] = pv[t] && ((unsigned)hh < (unsigned)H) && ((unsigned)ww < (unsigned)W);
            int p2 = v[t] ? (hh*W + ww) : 0;
            bp[t] = (const short8*)(Xn + (size_t)p2*Cin + kl);
        }
        for (int k0 = 0; k0 < Cin; k0 += 32) {
            int ko = k0 >> 3;
            short8 a  = ap[ko];
            short8 b0 = v[0] ? bp[0][ko] : zf;
            short8 b1 = v[1] ? bp[1][ko] : zf;
            short8 b2 = v[2] ? bp[2][ko] : zf;
            short8 b3 = v[3] ? bp[3][ko] : zf;
            acc0 = __builtin_amdgcn_mfma_f32_16x16x32_bf16(a, b0, acc0, 0, 0, 0);
            acc1 = __builtin_amdgcn_mfma_f32_16x16x32_bf16(a, b1, acc1, 0, 0, 0);
            acc2 = __builtin_amdgcn_mfma_f32_16x16x32_bf16(a, b2, acc2, 0, 0, 0);
            acc3 = __builtin_amdgcn_mfma_f32_16x16x32_bf16(a, b3, acc3, 0, 0, 0);
        }
    }

    if (Ws) {
        const unsigned short* X2n = Xs + (size_t)n * HW * Cs;
        const short8* ap = (const short8*)(Ws + ((size_t)(co64 + l15))*Cs + kl);
        const short8* bp[4];
        #pragma unroll
        for (int t = 0; t < 4; ++t) {
            int p2 = pv[t] ? (hh_[t]*W + ww_[t]) : 0;
            bp[t] = (const short8*)(X2n + (size_t)p2*Cs + kl);
        }
        for (int k0 = 0; k0 < Cs; k0 += 32) {
            int ko = k0 >> 3;
            short8 a  = ap[ko];
            short8 b0 = pv[0] ? bp[0][ko] : zf;
            short8 b1 = pv[1] ? bp[1][ko] : zf;
            short8 b2 = pv[2] ? bp[2][ko] : zf;
            short8 b3 = pv[3] ? bp[3][ko] : zf;
            acc0 = __builtin_amdgcn_mfma_f32_16x16x32_bf16(a, b0, acc0, 0, 0, 0);
            acc1 = __builtin_amdgcn_mfma_f32_16x16x32_bf16(a, b1, acc1, 0, 0, 0);
            acc2 = __builtin_amdgcn_mfma_f32_16x16x32_bf16(a, b2, acc2, 0, 0, 0);
            acc3 = __builtin_amdgcn_mfma_f32_16x16x32_bf16(a, b3, acc3, 0, 0, 0);
        }
    }

    int cb = co64 + (lane >> 4)*4;
    float s0 = g[cb+0]*RSQ, s1 = g[cb+1]*RSQ, s2 = g[cb+2]*RSQ, s3 = g[cb+3]*RSQ;
    float o0 = b[cb+0], o1 = b[cb+1], o2 = b[cb+2], o3 = b[cb+3];

#define EPI(ACC, T) do { \
    if (pv[T]) { \
        int px = px0 + (T)*16 + l15; \
        float v0 = ACC[0]*s0 + o0; v0 = (v0 >= 0.f) ? v0 : SLOPE*v0; \
        float v1 = ACC[1]*s1 + o1; v1 = (v1 >= 0.f) ? v1 : SLOPE*v1; \
        float v2 = ACC[2]*s2 + o2; v2 = (v2 >= 0.f) ? v2 : SLOPE*v2; \
        float v3 = ACC[3]*s3 + o3; v3 = (v3 >= 0.f) ? v3 : SLOPE*v3; \
        uint2 pk; \
        pk.x = (unsigned)f2bf(v0) | ((unsigned)f2bf(v1) << 16); \
        pk.y = (unsigned)f2bf(v2) | ((unsigned)f2bf(v3) << 16); \
        *(uint2*)(O + ((size_t)n*HW + px)*Cout + cb) = pk; \
    } \
} while(0)
    EPI(acc0, 0); EPI(acc1, 1); EPI(acc2, 2); EPI(acc3, 3);
#undef EPI
}

// ---------------- maxpool(1,4) VALID on NHWC bf16 (only for final 8->2) ----------------
__global__ void pool_nhwc_kernel(const unsigned short* __restrict__ in,
                                 unsigned short* __restrict__ out,
                                 int Win, int Wout, int WpO, int OOFF, int C, int total8)
{
    int idx = blockIdx.x*256 + threadIdx.x;
    if (idx >= total8) return;
    int c8 = idx % (C >> 3);
    int r = idx / (C >> 3);
    int w = r % Wout;
    int nh = r / Wout;
    const unsigned short* ip = in + (((size_t)nh*Win) + (size_t)w*4)*C + c8*8;
    float m0=-1e30f,m1=-1e30f,m2=-1e30f,m3=-1e30f,m4=-1e30f,m5=-1e30f,m6=-1e30f,m7=-1e30f;
    #pragma unroll
    for (int i = 0; i < 4; ++i) {
        uint4 u = *(const uint4*)(ip + (size_t)i*C);
        m0 = fmaxf(m0, bf2f((unsigned short)(u.x & 0xffff)));
        m1 = fmaxf(m1, bf2f((unsigned short)(u.x >> 16)));
        m2 = fmaxf(m2, bf2f((unsigned short)(u.y & 0xffff)));
        m3 = fmaxf(m3, bf2f((unsigned short)(u.y >> 16)));
        m4 = fmaxf(m4, bf2f((unsigned short)(u.z & 0xffff)));
        m5 = fmaxf(m5, bf2f((unsigned short)(u.z >> 16)));
        m6 = fmaxf(m6, bf2f((unsigned short)(u.w & 0xffff)));
        m7 = fmaxf(m7, bf2f((unsigned short)(u.w >> 16)));
    }
    uint4 ov;
    ov.x = (unsigned)f2bf(m0) | ((unsigned)f2bf(m1) << 16);
    ov.y = (unsigned)f2bf(m2) | ((unsigned)f2bf(m3) << 16);
    ov.z = (unsigned)f2bf(m4) | ((unsigned)f2bf(m5) << 16);
    ov.w = (unsigned)f2bf(m6) | ((unsigned)f2bf(m7) << 16);
    *(uint4*)(out + (((size_t)nh*WpO) + w + OOFF)*C + c8*8) = ov;
}

// ---------------- feats: [n][31][2][256] bf16 NHWC -> [n][31][512] fp32 ----------------
__global__ void feats_kernel(const unsigned short* __restrict__ p4, float* __restrict__ fe)
{
    int idx = blockIdx.x*256 + threadIdx.x;   // 507904
    int cw = idx & 511;
    int nh = idx >> 9;
    int c = cw >> 1, w = cw & 1;
    fe[idx] = bf2f(p4[((size_t)nh*2 + w)*256 + c]);
}

// ---------------- tiled SGEMM: C[M,N] = A[M,K] @ B[N,K]^T + bias(+bias2) ----------------
#define GM 32
#define GN 64
#define GK 32
template<int XPOSE>
__launch_bounds__(256)
__global__ void gemm_bias_kernel(const float* __restrict__ A, const float* __restrict__ B,
                                 const float* __restrict__ bias, const float* __restrict__ bias2,
                                 float* __restrict__ C, int M, int N, int K)
{
    __shared__ float As[GM][GK+1];
    __shared__ float Bs[GN][GK+1];
    int m0 = blockIdx.x*GM, n0 = blockIdx.y*GN;
    int tid = threadIdx.x;
    int mi = tid >> 4;
    int ni = (tid & 15) * 4;
    float acc[2][4] = {};

    for (int k0 = 0; k0 < K; k0 += GK) {
        for (int i = tid; i < GM*GK; i += 256) {
            int r = i >> 5, c = i & 31;
            int m = m0 + r;
            As[r][c] = (m < M) ? A[(size_t)m*K + k0 + c] : 0.f;
        }
        for (int i = tid; i < GN*GK; i += 256) {
            int r = i >> 5, c = i & 31;
            int n = n0 + r;
            Bs[r][c] = (n < N) ? B[(size_t)n*K + k0 + c] : 0.f;
        }
        __syncthreads();
        #pragma unroll
        for (int kk = 0; kk < GK; ++kk) {
            float a0 = As[mi][kk], a1 = As[mi+16][kk];
            float b0 = Bs[ni][kk], b1 = Bs[ni+1][kk], b2 = Bs[ni+2][kk], b3 = Bs[ni+3][kk];
            acc[0][0] += a0*b0; acc[0][1] += a0*b1; acc[0][2] += a0*b2; acc[0][3] += a0*b3;
            acc[1][0] += a1*b0; acc[1][1] += a1*b1; acc[1][2] += a1*b2; acc[1][3] += a1*b3;
        }
        __syncthreads();
    }
    #pragma unroll
    for (int r = 0; r < 2; ++r) {
        int m = m0 + mi + r*16;
        if (m >= M) continue;
        #pragma unroll
        for (int q = 0; q < 4; ++q) {
            int n = n0 + ni + q;
            if (n >= N) continue;
            float v = acc[r][q];
            if (bias)  v += bias[n];
            if (bias2) v += bias2[n];
            if (XPOSE) C[((size_t)(m % 31)*32 + (m / 31))*N + n] = v;
            else       C[(size_t)m*N + n] = v;
        }
    }
}

// ---------------- LSTM scan via MFMA + global_load_lds weight pipeline ----------------
// 4 blocks = (dir x batch-half), 1024 thr. Each wave double-buffers its own 4KB
// whh slice per kc through LDS (stage kc+1 while MFMA-consuming kc), counted vmcnt.
__launch_bounds__(1024)
__global__ void lstm_scan_mfma(const float* __restrict__ xpT,
                               const unsigned short* __restrict__ wf,
                               float* __restrict__ hcat)
{
    const int d  = blockIdx.x >> 1;
    const int bh = blockIdx.x & 1;
    const int tid = threadIdx.x;
    const int u0 = tid >> 6;
    const int lane = tid & 63;
    const int l15 = lane & 15;
    const int q = lane >> 4;

    __shared__ unsigned short hbuf[2][4096];          // 16 KB
    __shared__ unsigned short wst[16][2][2048];       // 128 KB: per-wave double buffer

    ((int4*)hbuf)[tid & 1023] = make_int4(0,0,0,0);
    // (zeroes both hbuf halves: 2*4096 ushorts = 1024 int4)

    const unsigned short* wfd = wf + (size_t)d*262144;
    const float* xpd = xpT + (size_t)d*992*1024 + (size_t)bh*16*1024;
    const unsigned short* wsrc = wfd + (size_t)u0*4096 + (size_t)lane*8;  // + g*65536 + kc*512
    unsigned short* wl = &wst[u0][0][0];

#define STAGE(KC, PB) do { \
    unsigned short* dst_ = wl + (PB)*2048; \
    stage16(wsrc + 0*65536 + (KC)*512, dst_ + 0*512); \
    stage16(wsrc + 1*65536 + (KC)*512, dst_ + 1*512); \
    stage16(wsrc + 2*65536 + (KC)*512, dst_ + 2*512); \
    stage16(wsrc + 3*65536 + (KC)*512, dst_ + 3*512); \
} while(0)

    STAGE(0, 0);
    __syncthreads();   // hbuf zero + (drains vmcnt before s_barrier)

    float c0=0.f, c1=0.f, c2=0.f, c3=0.f;
    const int ubase = u0*16 + q*4;
    const int rb = l15*512 + q*16;
    const int xr = (l15&7)<<4;

#define HRD(kc)   (*(const short8*)(hb + ((rb + (kc)*64) ^ xr)))
#define MF(w_,h_,a_) a_ = __builtin_amdgcn_mfma_f32_16x16x32_bf16(w_, h_, a_, 0, 0, 0)

    for (int s = 0; s < 31; ++s) {
        const int t = d ? (30 - s) : s;
        const int cur = s & 1, nxt = cur ^ 1;
        const float* xb = xpd + (size_t)t*32768 + (size_t)l15*1024;
        float4 xi = *(const float4*)(xb + ubase);
        float4 xf = *(const float4*)(xb + 256 + ubase);
        float4 xg = *(const float4*)(xb + 512 + ubase);
        float4 xo = *(const float4*)(xb + 768 + ubase);

        const char* hb = (const char*)hbuf[cur];
        f32x4 a0={0,0,0,0}, a1={0,0,0,0}, a2={0,0,0,0}, a3={0,0,0,0};

        #pragma unroll
        for (int kc = 0; kc < 8; ++kc) {
            // issue next slice (kc7 stages next step's kc0 -> buf0)
            if (kc < 7) STAGE(kc+1, (kc+1)&1);
            else        STAGE(0, 0);
            // allow the 4 just-issued (+4 xp at kc0) to stay outstanding
            if (kc == 0) asm volatile("s_waitcnt vmcnt(8)" ::: "memory");
            else         asm volatile("s_waitcnt vmcnt(4)" ::: "memory");
            const unsigned short* wb = wl + (kc&1)*2048;
            short8 w0 = *(const short8*)(wb + 0*512 + lane*8);
            short8 w1 = *(const short8*)(wb + 1*512 + lane*8);
            short8 w2 = *(const short8*)(wb + 2*512 + lane*8);
            short8 w3 = *(const short8*)(wb + 3*512 + lane*8);
            short8 h = HRD(kc);
            MF(w0,h,a0); MF(w1,h,a1); MF(w2,h,a2); MF(w3,h,a3);
        }

        float hv0, hv1, hv2, hv3;
        { float gi=a0[0]+xi.x, gf=a1[0]+xf.x, gg=a2[0]+xg.x, go=a3[0]+xo.x;
          float cn = sigmoidf_(gf)*c0 + sigmoidf_(gi)*tanhf(gg); c0 = cn; hv0 = sigmoidf_(go)*tanhf(cn); }
        { float gi=a0[1]+xi.y, gf=a1[1]+xf.y, gg=a2[1]+xg.y, go=a3[1]+xo.y;
          float cn = sigmoidf_(gf)*c1 + sigmoidf_(gi)*tanhf(gg); c1 = cn; hv1 = sigmoidf_(go)*tanhf(cn); }
        { float gi=a0[2]+xi.z, gf=a1[2]+xf.z, gg=a2[2]+xg.z, go=a3[2]+xo.z;
          float cn = sigmoidf_(gf)*c2 + sigmoidf_(gi)*tanhf(gg); c2 = cn; hv2 = sigmoidf_(go)*tanhf(cn); }
        { float gi=a0[3]+xi.w, gf=a1[3]+xf.w, gg=a2[3]+xg.w, go=a3[3]+xo.w;
          float cn = sigmoidf_(gf)*c3 + sigmoidf_(gi)*tanhf(gg); c3 = cn; hv3 = sigmoidf_(go)*tanhf(cn); }

        short4 hp;
        hp.x = (short)f2bf(hv0); hp.y = (short)f2bf(hv1);
        hp.z = (short)f2bf(hv2); hp.w = (short)f2bf(hv3);
        *(short4*)((char*)hbuf[nxt] + ((l15*512 + ubase*2) ^ xr)) = hp;
        int bg = bh*16 + l15;
        *(float4*)(&hcat[((size_t)bg*31 + t)*512 + (size_t)d*256 + ubase]) =
            make_float4(hv0, hv1, hv2, hv3);

        __syncthreads();
    }
#undef STAGE
#undef HRD
#undef MF
}

extern "C" void kernel_launch(void* const* d_in, const int* in_sizes, int n_in,
                              void* d_out, int out_size, void* d_ws, size_t ws_size,
                              hipStream_t stream)
{
    const float* x    = (const float*)d_in[0];
    const float* fW   = (const float*)d_in[1];
    const float* fB   = (const float*)d_in[2];
    const float* cbw1 = (const float*)d_in[3];
    const float* cbg  = (const float*)d_in[4];
    const float* cbb  = (const float*)d_in[5];
    const float* cbw2 = (const float*)d_in[6];
    const float* r1pg = (const float*)d_in[7];
    const float* r1pb = (const float*)d_in[8];
    const float* r1wA = (const float*)d_in[9];
    const float* r1g  = (const float*)d_in[10];
    const float* r1b  = (const float*)d_in[11];
    const float* r1wB = (const float*)d_in[12];
    const float* r1s  = (const float*)d_in[13];
    const float* r2pg = (const float*)d_in[14];
    const float* r2pb = (const float*)d_in[15];
    const float* r2wA = (const float*)d_in[16];
    const float* r2g  = (const float*)d_in[17];
    const float* r2b  = (const float*)d_in[18];
    const float* r2wB = (const float*)d_in[19];
    const float* r2s  = (const float*)d_in[20];
    const float* r3pg = (const float*)d_in[21];
    const float* r3pb = (const float*)d_in[22];
    const float* r3wA = (const float*)d_in[23];
    const float* r3g  = (const float*)d_in[24];
    const float* r3b  = (const float*)d_in[25];
    const float* r3wB = (const float*)d_in[26];
    const float* r3s  = (const float*)d_in[27];
    const float* pbg  = (const float*)d_in[28];
    const float* pbb  = (const float*)d_in[29];
    const float* wih_f = (const float*)d_in[30];
    const float* whh_f = (const float*)d_in[31];
    const float* bih_f = (const float*)d_in[32];
    const float* bhh_f = (const float*)d_in[33];
    const float* wih_b = (const float*)d_in[34];
    const float* whh_b = (const float*)d_in[35];
    const float* bih_b = (const float*)d_in[36];
    const float* bhh_b = (const float*)d_in[37];
    const float* clsw  = (const float*)d_in[38];
    const float* clsb  = (const float*)d_in[39];
    float* out = (float*)d_out;
    float* ws  = (float*)d_ws;

    // ---- workspace sizing ----
    const size_t FIXEDF = 5543872;
    const size_t PADDED_SHORTS = 2270400;   // A1..A3, memset region
    const size_t PCS = 2444992;             // all per-img shorts
    const size_t PCF = (PCS + 1)/2;
    int NC = 0;
    const int cands[6] = {32,16,8,4,2,1};
    for (int i = 0; i < 6; ++i) {
        if ((FIXEDF + (size_t)cands[i]*PCF + 64)*sizeof(float) <= ws_size) { NC = cands[i]; break; }
    }
    if (!NC) return;

    float* p = ws;
    unsigned short* WTR = (unsigned short*)p; p += 962560;
    float* P   = p; p += 508896;
    float* XM  = p; p += 508896;
    unsigned short* XP4 = (unsigned short*)p; p += 253952;
    float* FE  = p; p += 507904;
    unsigned short* WF = (unsigned short*)p; p += 262144;
    float* XPT = p; p += 2031616;
    float* HC  = p; p += 507904;
    unsigned short* q = (unsigned short*)p;
    unsigned short* A1  = q; q += (size_t)NC*1087680;
    unsigned short* C1p = q; q += (size_t)NC*274560;
    unsigned short* A2  = q; q += (size_t)NC*549120;
    unsigned short* C2p = q; q += (size_t)NC*143616;
    unsigned short* A3  = q; q += (size_t)NC*215424;
    unsigned short* XP3 = q; q += (size_t)NC*47616;
    unsigned short* A4  = q; q += (size_t)NC*63488;
    unsigned short* B4  = q; q += (size_t)NC*63488;

    unsigned short* w2T  = WTR + 0;
    unsigned short* r1AT = WTR + 36864;
    unsigned short* r1BT = WTR + 110592;
    unsigned short* r1ST = WTR + 258048;
    unsigned short* r2AT = WTR + 266240;
    unsigned short* r2BT = WTR + 487424;
    unsigned short* r2ST = WTR + 819200;
    unsigned short* r3AT = WTR + 843776;
    unsigned short* r3BT = WTR + 1286144;
    unsigned short* r3ST = WTR + 1875968;

    auto cdiv = [](int a, int b){ return (a + b - 1) / b; };

    // ---- weight transforms ----
    wtrans9_kernel<<<cdiv(9*64*64,256),   256, 0, stream>>>(cbw2, w2T, 64, 64);
    wtrans9_kernel<<<cdiv(9*128*64,256),  256, 0, stream>>>(r1wA, r1AT, 128, 64);
    wtrans9_kernel<<<cdiv(9*128*128,256), 256, 0, stream>>>(r1wB, r1BT, 128, 128);
    wtrans1_kernel<<<cdiv(128*64,256),    256, 0, stream>>>(r1s, r1ST, 128*64);
    wtrans9_kernel<<<cdiv(9*192*128,256), 256, 0, stream>>>(r2wA, r2AT, 192, 128);
    wtrans9_kernel<<<cdiv(9*192*192,256), 256, 0, stream>>>(r2wB, r2BT, 192, 192);
    wtrans1_kernel<<<cdiv(192*128,256),   256, 0, stream>>>(r2s, r2ST, 192*128);
    wtrans9_kernel<<<cdiv(9*256*192,256), 256, 0, stream>>>(r3wA, r3AT, 256, 192);
    wtrans9_kernel<<<cdiv(9*256*256,256), 256, 0, stream>>>(r3wB, r3BT, 256, 256);
    wtrans1_kernel<<<cdiv(256*192,256),   256, 0, stream>>>(r3s, r3ST, 256*192);
    whh_frag_kernel<<<1024, 256, 0, stream>>>(whh_f, WF);
    whh_frag_kernel<<<1024, 256, 0, stream>>>(whh_b, WF + 262144);

    // ---- frontend mask ----
    mask_partial_kernel<<<dim3(63, 32), 256, 0, stream>>>(fW, fB, P);
    mask_finalize_apply<<<63, 256, 0, stream>>>(P, x, XM);

    // ---- zero padded staging region (h/w halos stay zero) ----
    hipMemsetAsync(A1, 0, (size_t)NC*PADDED_SHORTS*sizeof(unsigned short), stream);

    // ---- conv stack, chunked over batch ----
    for (int c0 = 0; c0 < 32; c0 += NC) {
        const float* xmc = XM + (size_t)c0*15903;
        conv1_kernel<<<dim3(63, 1, NC), 256, 0, stream>>>(xmc, cbw1, cbg, cbb, A1);
        conv_lds_kernel<64,8,0,1><<<dim3(4*31, 1, NC), 256, 0, stream>>>(
            A1, w2T, nullptr, nullptr, C1p, 515, 4, 0, 33, 1, 130, 1, 64, r1pg, r1pb);
        conv_lds_kernel<64,8,0,0><<<dim3(31, 2, NC), 256, 0, stream>>>(
            C1p, r1AT, nullptr, nullptr, A2, 130, 1, 0, 33, 1, 130, 1, 128, r1g, r1b);
        conv_lds_kernel<128,8,64,1><<<dim3(31, 2, NC), 256, 0, stream>>>(
            A2, r1BT, C1p, r1ST, C2p, 130, 1, 130, 33, 1, 34, 1, 128, r2pg, r2pb);
        conv_lds_kernel<128,2,0,0><<<dim3(31, 3, NC), 256, 0, stream>>>(
            C2p, r2AT, nullptr, nullptr, A3, 34, 1, 0, 33, 1, 34, 1, 192, r2g, r2b);
        conv_lds_kernel<192,2,128,1><<<dim3(31, 3, NC), 256, 0, stream>>>(
            A3, r2BT, C2p, r2ST, XP3, 34, 1, 34, 31, 0, 8, 0, 192, r3pg, r3pb);
        conv_mfma_kernel<<<dim3(4, 4, NC), 256, 0, stream>>>(
            XP3, r3AT, nullptr, nullptr, A4, 31, 8, 192, 0, 256, r3g, r3b);
        conv_mfma_kernel<<<dim3(4, 4, NC), 256, 0, stream>>>(
            A4, r3BT, XP3, r3ST, B4, 31, 8, 256, 192, 256, pbg, pbb);
        pool_nhwc_kernel<<<cdiv(NC*31*2*32,256), 256, 0, stream>>>(
            B4, XP4 + (size_t)c0*15872, 8, 2, 2, 0, 256, NC*31*2*32);
    }

    // feats (32,31,512) fp32
    feats_kernel<<<1984, 256, 0, stream>>>(XP4, FE);

    // LSTM input projections -> xpT [d][t][b][j]
    gemm_bias_kernel<1><<<dim3(31, 16), 256, 0, stream>>>(FE, wih_f, bih_f, bhh_f, XPT,           992, 1024, 512);
    gemm_bias_kernel<1><<<dim3(31, 16), 256, 0, stream>>>(FE, wih_b, bih_b, bhh_b, XPT + 1015808, 992, 1024, 512);

    // fused bidirectional scan (4 blocks: dir x batch-half)
    lstm_scan_mfma<<<4, 1024, 0, stream>>>(XPT, WF, HC);

    // classifier -> d_out (32,31,722)
    gemm_bias_kernel<0><<<dim3(31, 12), 256, 0, stream>>>(HC, clsw, clsb, nullptr, out, 992, 722, 512);
}